// Round 1
// baseline (5832.382 us; speedup 1.0000x reference)
//
#include <hip/hip_runtime.h>

#define NN 100000
#define NE 1600000
#define NF 128
#define GR 32   // rows staged per GEMM block-iteration

// ---------------- degree count (int atomics) ----------------
__global__ __launch_bounds__(256) void k_deg(const int* __restrict__ row,
                                             int* __restrict__ deg) {
    int e = blockIdx.x * 256 + threadIdx.x;
    if (e < NE) atomicAdd(deg + row[e], 1);
}

// ---------------- dinv = deg>0 ? rsqrt(deg) : 0 ----------------
__global__ __launch_bounds__(256) void k_dinv(const int* __restrict__ deg,
                                              float* __restrict__ dinv) {
    int i = blockIdx.x * 256 + threadIdx.x;
    if (i < NN) {
        int d = deg[i];
        dinv[i] = d > 0 ? rsqrtf((float)d) : 0.0f;
    }
}

// ---------------- SpMM: tx[row] += -(dinv[row]*dinv[col]) * x[col] ----------------
// 32 threads per edge, float4 per thread (128 feats). fp32 HW atomics.
__global__ __launch_bounds__(256) void k_spmm(const int* __restrict__ row,
                                              const int* __restrict__ col,
                                              const float* __restrict__ dinv,
                                              const float* __restrict__ x,
                                              float* __restrict__ tx) {
    int t = blockIdx.x * 256 + threadIdx.x;
    int e = t >> 5;
    if (e >= NE) return;
    int f = (threadIdx.x & 31) * 4;
    int r = row[e];
    int c = col[e];
    float w = -(dinv[r] * dinv[c]);
    const float4 v = *reinterpret_cast<const float4*>(x + c * NF + f);
    float* dst = tx + r * NF + f;
    __hip_atomic_fetch_add(dst + 0, w * v.x, __ATOMIC_RELAXED, __HIP_MEMORY_SCOPE_AGENT);
    __hip_atomic_fetch_add(dst + 1, w * v.y, __ATOMIC_RELAXED, __HIP_MEMORY_SCOPE_AGENT);
    __hip_atomic_fetch_add(dst + 2, w * v.z, __ATOMIC_RELAXED, __HIP_MEMORY_SCOPE_AGENT);
    __hip_atomic_fetch_add(dst + 3, w * v.w, __ATOMIC_RELAXED, __HIP_MEMORY_SCOPE_AGENT);
}

// ---------------- fused dual-GEMM + bias + relu (+ optional residual combine) ----
// out = relu(A@W0 + T@W1 + b)          (combine == 0)
// out = 0.5*(A + relu(A@W0 + T@W1 + b))  (combine == 1; A rows re-read from LDS)
// Block: 256 threads; W0,W1 fully LDS-resident (128 KB); 32 A/T rows staged (32 KB).
// Thread tile: 4 rows x 4 cols. Each block owns disjoint row-blocks -> safe even
// when out aliases A (layer 2).
__global__ __launch_bounds__(256) void k_gemm(const float* __restrict__ A,
                                              const float* __restrict__ T,
                                              const float* __restrict__ W0,
                                              const float* __restrict__ W1,
                                              const float* __restrict__ bias,
                                              float* __restrict__ out,
                                              int combine) {
    __shared__ float w0s[128][128];
    __shared__ float w1s[128][128];
    __shared__ float as[GR][128];
    __shared__ float ts[GR][128];

    // stage weights once per block
    float* w0f = &w0s[0][0];
    float* w1f = &w1s[0][0];
    for (int i = threadIdx.x * 4; i < 128 * 128; i += 256 * 4) {
        *(float4*)(w0f + i) = *(const float4*)(W0 + i);
        *(float4*)(w1f + i) = *(const float4*)(W1 + i);
    }

    const int cg = threadIdx.x & 31;   // 32 col-groups of 4 cols
    const int rg = threadIdx.x >> 5;   // 8 row-groups of 4 rows
    const int c0 = cg * 4;
    const int r0 = rg * 4;
    const float4 bv = *(const float4*)(bias + c0);

    __syncthreads();

    for (int rb = blockIdx.x * GR; rb < NN; rb += gridDim.x * GR) {
        __syncthreads();   // previous iteration fully consumed LDS
        // stage GR rows of A and T (32 float4 per row)
        for (int i = threadIdx.x; i < GR * 32; i += 256) {
            int rr = i >> 5;
            int kk = (i & 31) * 4;
            *(float4*)&as[rr][kk] = *(const float4*)(A + (rb + rr) * NF + kk);
            *(float4*)&ts[rr][kk] = *(const float4*)(T + (rb + rr) * NF + kk);
        }
        __syncthreads();

        float acc[4][4];
#pragma unroll
        for (int j = 0; j < 4; ++j) {
            acc[j][0] = bv.x; acc[j][1] = bv.y; acc[j][2] = bv.z; acc[j][3] = bv.w;
        }

        for (int k = 0; k < 128; k += 4) {
            float av[4][4], tv[4][4];
#pragma unroll
            for (int j = 0; j < 4; ++j) {
                *(float4*)av[j] = *(const float4*)&as[r0 + j][k];
                *(float4*)tv[j] = *(const float4*)&ts[r0 + j][k];
            }
#pragma unroll
            for (int kk = 0; kk < 4; ++kk) {
                const float4 w0v = *(const float4*)&w0s[k + kk][c0];
                const float4 w1v = *(const float4*)&w1s[k + kk][c0];
                const float w0a[4] = {w0v.x, w0v.y, w0v.z, w0v.w};
                const float w1a[4] = {w1v.x, w1v.y, w1v.z, w1v.w};
#pragma unroll
                for (int j = 0; j < 4; ++j)
#pragma unroll
                    for (int i = 0; i < 4; ++i)
                        acc[j][i] += av[j][kk] * w0a[i] + tv[j][kk] * w1a[i];
            }
        }

        // epilogue: relu (+ combine), float4 store
#pragma unroll
        for (int j = 0; j < 4; ++j) {
            float4 o;
            float* oo = (float*)&o;
#pragma unroll
            for (int i = 0; i < 4; ++i) {
                float v = acc[j][i] > 0.0f ? acc[j][i] : 0.0f;
                if (combine) v = 0.5f * (as[r0 + j][c0 + i] + v);
                oo[i] = v;
            }
            *(float4*)(out + (rb + r0 + j) * NF + c0) = o;
        }
    }
}

extern "C" void kernel_launch(void* const* d_in, const int* in_sizes, int n_in,
                              void* d_out, int out_size, void* d_ws, size_t ws_size,
                              hipStream_t stream) {
    const float* x   = (const float*)d_in[0];
    const int*   ei  = (const int*)d_in[1];
    const float* W01 = (const float*)d_in[2];
    const float* W11 = (const float*)d_in[3];
    const float* b1  = (const float*)d_in[4];
    const float* W02 = (const float*)d_in[5];
    const float* W12 = (const float*)d_in[6];
    const float* b2  = (const float*)d_in[7];
    float* out = (float*)d_out;

    const int* row = ei;        // edge_index[0]
    const int* col = ei + NE;   // edge_index[1]

    // workspace layout: deg (int, 400000B) | dinv (float, 400000B) | tx (N*128 f32)
    char* ws = (char*)d_ws;
    int*   deg  = (int*)ws;
    float* dinv = (float*)(ws + 400000);
    float* tx   = (float*)(ws + 800000);
    const size_t txBytes = (size_t)NN * NF * sizeof(float);

    hipMemsetAsync(deg, 0, (size_t)NN * sizeof(int), stream);
    hipMemsetAsync(tx, 0, txBytes, stream);

    k_deg<<<NE / 256, 256, 0, stream>>>(row, deg);
    k_dinv<<<(NN + 255) / 256, 256, 0, stream>>>(deg, dinv);

    // layer 1: tx = L_hat x ; x1 = relu(x@W0_1 + tx@W1_1 + b1) -> d_out
    k_spmm<<<(NE * 32) / 256, 256, 0, stream>>>(row, col, dinv, x, tx);
    k_gemm<<<256, 256, 0, stream>>>(x, tx, W01, W11, b1, out, 0);

    // layer 2: tx = L_hat x1 ; out = 0.5*(x1 + relu(x1@W0_2 + tx@W1_2 + b2))
    hipMemsetAsync(tx, 0, txBytes, stream);
    k_spmm<<<(NE * 32) / 256, 256, 0, stream>>>(row, col, dinv, out, tx);
    k_gemm<<<256, 256, 0, stream>>>(out, tx, W02, W12, b2, out, 1);
}

// Round 2
// 1056.335 us; speedup vs baseline: 5.5213x; 5.5213x over previous
//
#include <hip/hip_runtime.h>

#define NN 100000
#define NE 1600000
#define NF 128
#define GR 32   // rows staged per GEMM block-iteration

// ---------------- degree count (int atomics) ----------------
__global__ __launch_bounds__(256) void k_deg(const int* __restrict__ row,
                                             int* __restrict__ deg) {
    int e = blockIdx.x * 256 + threadIdx.x;
    if (e < NE) atomicAdd(deg + row[e], 1);
}

// ---------------- dinv = deg>0 ? rsqrt(deg) : 0 ----------------
__global__ __launch_bounds__(256) void k_dinv(const int* __restrict__ deg,
                                              float* __restrict__ dinv) {
    int i = blockIdx.x * 256 + threadIdx.x;
    if (i < NN) {
        int d = deg[i];
        dinv[i] = d > 0 ? rsqrtf((float)d) : 0.0f;
    }
}

// ---------------- single-block exclusive scan of deg -> offs, cursor --------
__global__ __launch_bounds__(1024) void k_scan(const int* __restrict__ deg,
                                               int* __restrict__ offs,
                                               int* __restrict__ cursor) {
    __shared__ int part[1024];
    const int chunk = (NN + 1023) / 1024;          // 98
    const int t = threadIdx.x;
    const int beg = t * chunk;
    const int end = min(beg + chunk, NN);
    int s = 0;
    for (int i = beg; i < end; ++i) s += deg[i];
    part[t] = s;
    __syncthreads();
    if (t == 0) {                                  // serial scan of 1024 partials
        int run = 0;
        for (int i = 0; i < 1024; ++i) { int v = part[i]; part[i] = run; run += v; }
    }
    __syncthreads();
    int run = part[t];
    for (int i = beg; i < end; ++i) {
        offs[i] = run; cursor[i] = run; run += deg[i];
    }
    if (t == 1023) offs[NN] = run;                 // == NE
}

// ---------------- scatter cols into CSR slots ----------------
__global__ __launch_bounds__(256) void k_scatter(const int* __restrict__ row,
                                                 const int* __restrict__ col,
                                                 int* __restrict__ cursor,
                                                 int* __restrict__ ccol) {
    int e = blockIdx.x * 256 + threadIdx.x;
    if (e < NE) {
        int pos = atomicAdd(cursor + row[e], 1);
        ccol[pos] = col[e];
    }
}

// ---------------- gather SpMM: tx[r] = -dinv[r] * sum_j dinv[c_j] x[c_j] ----
// one 64-lane wave per row; lane owns 2 feats (float2). No atomics.
__global__ __launch_bounds__(256) void k_gather(const int* __restrict__ offs,
                                                const int* __restrict__ ccol,
                                                const float* __restrict__ dinv,
                                                const float* __restrict__ x,
                                                float* __restrict__ tx) {
    int r = (blockIdx.x * 256 + threadIdx.x) >> 6;  // wave id = row
    if (r >= NN) return;
    int lane = threadIdx.x & 63;
    int beg = offs[r], end = offs[r + 1];
    const float2* x2 = (const float2*)x;
    float2 acc = {0.0f, 0.0f};
    int j = beg;
    for (; j + 1 < end; j += 2) {                   // unroll-2 for load ILP
        int c0 = ccol[j], c1 = ccol[j + 1];
        float w0 = dinv[c0], w1 = dinv[c1];
        float2 v0 = x2[c0 * 64 + lane];
        float2 v1 = x2[c1 * 64 + lane];
        acc.x += w0 * v0.x + w1 * v1.x;
        acc.y += w0 * v0.y + w1 * v1.y;
    }
    if (j < end) {
        int c = ccol[j];
        float w = dinv[c];
        float2 v = x2[c * 64 + lane];
        acc.x += w * v.x;
        acc.y += w * v.y;
    }
    float s = -dinv[r];
    float2 o = {s * acc.x, s * acc.y};
    ((float2*)tx)[r * 64 + lane] = o;
}

// ---------------- fused dual-GEMM + bias + relu (+ optional combine) --------
__global__ __launch_bounds__(256) void k_gemm(const float* __restrict__ A,
                                              const float* __restrict__ T,
                                              const float* __restrict__ W0,
                                              const float* __restrict__ W1,
                                              const float* __restrict__ bias,
                                              float* __restrict__ out,
                                              int combine) {
    __shared__ float w0s[128][128];
    __shared__ float w1s[128][128];
    __shared__ float as[GR][128];
    __shared__ float ts[GR][128];

    float* w0f = &w0s[0][0];
    float* w1f = &w1s[0][0];
    for (int i = threadIdx.x * 4; i < 128 * 128; i += 256 * 4) {
        *(float4*)(w0f + i) = *(const float4*)(W0 + i);
        *(float4*)(w1f + i) = *(const float4*)(W1 + i);
    }

    const int cg = threadIdx.x & 31;
    const int rg = threadIdx.x >> 5;
    const int c0 = cg * 4;
    const int r0 = rg * 4;
    const float4 bv = *(const float4*)(bias + c0);

    __syncthreads();

    for (int rb = blockIdx.x * GR; rb < NN; rb += gridDim.x * GR) {
        __syncthreads();
        for (int i = threadIdx.x; i < GR * 32; i += 256) {
            int rr = i >> 5;
            int kk = (i & 31) * 4;
            *(float4*)&as[rr][kk] = *(const float4*)(A + (rb + rr) * NF + kk);
            *(float4*)&ts[rr][kk] = *(const float4*)(T + (rb + rr) * NF + kk);
        }
        __syncthreads();

        float acc[4][4];
#pragma unroll
        for (int j = 0; j < 4; ++j) {
            acc[j][0] = bv.x; acc[j][1] = bv.y; acc[j][2] = bv.z; acc[j][3] = bv.w;
        }

        for (int k = 0; k < 128; k += 4) {
            float av[4][4], tv[4][4];
#pragma unroll
            for (int j = 0; j < 4; ++j) {
                *(float4*)av[j] = *(const float4*)&as[r0 + j][k];
                *(float4*)tv[j] = *(const float4*)&ts[r0 + j][k];
            }
#pragma unroll
            for (int kk = 0; kk < 4; ++kk) {
                const float4 w0v = *(const float4*)&w0s[k + kk][c0];
                const float4 w1v = *(const float4*)&w1s[k + kk][c0];
                const float w0a[4] = {w0v.x, w0v.y, w0v.z, w0v.w};
                const float w1a[4] = {w1v.x, w1v.y, w1v.z, w1v.w};
#pragma unroll
                for (int j = 0; j < 4; ++j)
#pragma unroll
                    for (int i = 0; i < 4; ++i)
                        acc[j][i] += av[j][kk] * w0a[i] + tv[j][kk] * w1a[i];
            }
        }

#pragma unroll
        for (int j = 0; j < 4; ++j) {
            float4 o;
            float* oo = (float*)&o;
#pragma unroll
            for (int i = 0; i < 4; ++i) {
                float v = acc[j][i] > 0.0f ? acc[j][i] : 0.0f;
                if (combine) v = 0.5f * (as[r0 + j][c0 + i] + v);
                oo[i] = v;
            }
            *(float4*)(out + (rb + r0 + j) * NF + c0) = o;
        }
    }
}

extern "C" void kernel_launch(void* const* d_in, const int* in_sizes, int n_in,
                              void* d_out, int out_size, void* d_ws, size_t ws_size,
                              hipStream_t stream) {
    const float* x   = (const float*)d_in[0];
    const int*   ei  = (const int*)d_in[1];
    const float* W01 = (const float*)d_in[2];
    const float* W11 = (const float*)d_in[3];
    const float* b1  = (const float*)d_in[4];
    const float* W02 = (const float*)d_in[5];
    const float* W12 = (const float*)d_in[6];
    const float* b2  = (const float*)d_in[7];
    float* out = (float*)d_out;

    const int* row = ei;        // edge_index[0]
    const int* col = ei + NE;   // edge_index[1]

    // ws layout (bytes):
    //   deg    @ 0         (400000)
    //   dinv   @ 400000    (400000)
    //   offs   @ 800000    (400016, NN+1 ints padded)
    //   cursor @ 1200016   (400000)
    //   ccol   @ 1600016   (6400000)  [16B aligned]
    //   tx     @ 8000016   (51200000) [16B aligned]
    char* ws = (char*)d_ws;
    int*   deg    = (int*)(ws);
    float* dinv   = (float*)(ws + 400000);
    int*   offs   = (int*)(ws + 800000);
    int*   cursor = (int*)(ws + 1200016);
    int*   ccol   = (int*)(ws + 1600016);
    float* tx     = (float*)(ws + 8000016);

    hipMemsetAsync(deg, 0, (size_t)NN * sizeof(int), stream);

    k_deg    <<<NE / 256, 256, 0, stream>>>(row, deg);
    k_dinv   <<<(NN + 255) / 256, 256, 0, stream>>>(deg, dinv);
    k_scan   <<<1, 1024, 0, stream>>>(deg, offs, cursor);
    k_scatter<<<NE / 256, 256, 0, stream>>>(row, col, cursor, ccol);

    const int gatherBlocks = (NN * 64 + 255) / 256;  // 1 wave per row

    // layer 1
    k_gather<<<gatherBlocks, 256, 0, stream>>>(offs, ccol, dinv, x, tx);
    k_gemm  <<<256, 256, 0, stream>>>(x, tx, W01, W11, b1, out, 0);

    // layer 2 (x1 lives in d_out; block-disjoint rows make in-place safe)
    k_gather<<<gatherBlocks, 256, 0, stream>>>(offs, ccol, dinv, out, tx);
    k_gemm  <<<256, 256, 0, stream>>>(out, tx, W02, W12, b2, out, 1);
}

// Round 3
// 774.185 us; speedup vs baseline: 7.5336x; 1.3644x over previous
//
#include <hip/hip_runtime.h>

#define NN 100000
#define NE 1600000
#define NF 128
#define GR 32             // rows staged per GEMM block-iteration
#define NBLK ((NN + 255) / 256)   // 391 scan blocks

// ---------------- degree count (int atomics) ----------------
__global__ __launch_bounds__(256) void k_deg(const int* __restrict__ row,
                                             int* __restrict__ deg) {
    int e = blockIdx.x * 256 + threadIdx.x;
    if (e < NE) atomicAdd(deg + row[e], 1);
}

// ---------------- dinv = deg>0 ? rsqrt(deg) : 0 ----------------
__global__ __launch_bounds__(256) void k_dinv(const int* __restrict__ deg,
                                              float* __restrict__ dinv) {
    int i = blockIdx.x * 256 + threadIdx.x;
    if (i < NN) {
        int d = deg[i];
        dinv[i] = d > 0 ? rsqrtf((float)d) : 0.0f;
    }
}

// ---------------- scan phase 1: per-block sums ----------------
__global__ __launch_bounds__(256) void k_scan1(const int* __restrict__ deg,
                                               int* __restrict__ bsum) {
    __shared__ int s[256];
    int t = threadIdx.x;
    int i = blockIdx.x * 256 + t;
    s[t] = i < NN ? deg[i] : 0;
    __syncthreads();
    for (int off = 128; off > 0; off >>= 1) {
        if (t < off) s[t] += s[t + off];
        __syncthreads();
    }
    if (t == 0) bsum[blockIdx.x] = s[0];
}

// ---------------- scan phase 2: exclusive scan of block sums ----------------
__global__ __launch_bounds__(256) void k_scan2(int* __restrict__ bsum) {
    __shared__ int s[NBLK];
    int t = threadIdx.x;
    for (int i = t; i < NBLK; i += 256) s[i] = bsum[i];
    __syncthreads();
    if (t == 0) {
        int run = 0;
        for (int i = 0; i < NBLK; ++i) { int v = s[i]; s[i] = run; run += v; }
    }
    __syncthreads();
    for (int i = t; i < NBLK; i += 256) bsum[i] = s[i];
}

// ---------------- scan phase 3: block-local scan + base -> offs, cursor -----
__global__ __launch_bounds__(256) void k_scan3(const int* __restrict__ deg,
                                               const int* __restrict__ bsum,
                                               int* __restrict__ offs,
                                               int* __restrict__ cursor) {
    __shared__ int s[256];
    int t = threadIdx.x;
    int i = blockIdx.x * 256 + t;
    int v = i < NN ? deg[i] : 0;
    s[t] = v;
    __syncthreads();
    for (int off = 1; off < 256; off <<= 1) {
        int u = (t >= off) ? s[t - off] : 0;
        __syncthreads();
        s[t] += u;
        __syncthreads();
    }
    int pos = bsum[blockIdx.x] + s[t] - v;          // exclusive
    if (i < NN) { offs[i] = pos; cursor[i] = pos; }
    if (i == 0) offs[NN] = NE;
}

// ---------------- scatter cols into CSR slots ----------------
__global__ __launch_bounds__(256) void k_scatter(const int* __restrict__ row,
                                                 const int* __restrict__ col,
                                                 int* __restrict__ cursor,
                                                 int* __restrict__ ccol) {
    int e = blockIdx.x * 256 + threadIdx.x;
    if (e < NE) {
        int pos = atomicAdd(cursor + row[e], 1);
        ccol[pos] = col[e];
    }
}

// ---------------- gather SpMM: tx[r] = -dinv[r] * sum_j dinv[c_j] x[c_j] ----
// one 64-lane wave per row; lane owns 2 feats (float2). No atomics. unroll-4.
__global__ __launch_bounds__(256) void k_gather(const int* __restrict__ offs,
                                                const int* __restrict__ ccol,
                                                const float* __restrict__ dinv,
                                                const float* __restrict__ x,
                                                float* __restrict__ tx) {
    int r = (blockIdx.x * 256 + threadIdx.x) >> 6;  // wave id = row
    if (r >= NN) return;
    int lane = threadIdx.x & 63;
    int beg = offs[r], end = offs[r + 1];
    const float2* x2 = (const float2*)x;
    float2 acc = {0.0f, 0.0f};
    int j = beg;
    for (; j + 3 < end; j += 4) {
        int c0 = ccol[j], c1 = ccol[j + 1], c2 = ccol[j + 2], c3 = ccol[j + 3];
        float w0 = dinv[c0], w1 = dinv[c1], w2 = dinv[c2], w3 = dinv[c3];
        float2 v0 = x2[c0 * 64 + lane];
        float2 v1 = x2[c1 * 64 + lane];
        float2 v2 = x2[c2 * 64 + lane];
        float2 v3 = x2[c3 * 64 + lane];
        acc.x += w0 * v0.x + w1 * v1.x + w2 * v2.x + w3 * v3.x;
        acc.y += w0 * v0.y + w1 * v1.y + w2 * v2.y + w3 * v3.y;
    }
    for (; j < end; ++j) {
        int c = ccol[j];
        float w = dinv[c];
        float2 v = x2[c * 64 + lane];
        acc.x += w * v.x;
        acc.y += w * v.y;
    }
    float s = -dinv[r];
    float2 o = {s * acc.x, s * acc.y};
    ((float2*)tx)[r * 64 + lane] = o;
}

// ---------------- fused dual-GEMM + bias + relu (+ optional combine) --------
__global__ __launch_bounds__(256) void k_gemm(const float* __restrict__ A,
                                              const float* __restrict__ T,
                                              const float* __restrict__ W0,
                                              const float* __restrict__ W1,
                                              const float* __restrict__ bias,
                                              float* __restrict__ out,
                                              int combine) {
    __shared__ float w0s[128][128];
    __shared__ float w1s[128][128];
    __shared__ float as[GR][128];
    __shared__ float ts[GR][128];

    float* w0f = &w0s[0][0];
    float* w1f = &w1s[0][0];
    for (int i = threadIdx.x * 4; i < 128 * 128; i += 256 * 4) {
        *(float4*)(w0f + i) = *(const float4*)(W0 + i);
        *(float4*)(w1f + i) = *(const float4*)(W1 + i);
    }

    const int cg = threadIdx.x & 31;
    const int rg = threadIdx.x >> 5;
    const int c0 = cg * 4;
    const int r0 = rg * 4;
    const float4 bv = *(const float4*)(bias + c0);

    __syncthreads();

    for (int rb = blockIdx.x * GR; rb < NN; rb += gridDim.x * GR) {
        __syncthreads();
        for (int i = threadIdx.x; i < GR * 32; i += 256) {
            int rr = i >> 5;
            int kk = (i & 31) * 4;
            *(float4*)&as[rr][kk] = *(const float4*)(A + (rb + rr) * NF + kk);
            *(float4*)&ts[rr][kk] = *(const float4*)(T + (rb + rr) * NF + kk);
        }
        __syncthreads();

        float acc[4][4];
#pragma unroll
        for (int j = 0; j < 4; ++j) {
            acc[j][0] = bv.x; acc[j][1] = bv.y; acc[j][2] = bv.z; acc[j][3] = bv.w;
        }

        for (int k = 0; k < 128; k += 4) {
            float av[4][4], tv[4][4];
#pragma unroll
            for (int j = 0; j < 4; ++j) {
                *(float4*)av[j] = *(const float4*)&as[r0 + j][k];
                *(float4*)tv[j] = *(const float4*)&ts[r0 + j][k];
            }
#pragma unroll
            for (int kk = 0; kk < 4; ++kk) {
                const float4 w0v = *(const float4*)&w0s[k + kk][c0];
                const float4 w1v = *(const float4*)&w1s[k + kk][c0];
                const float w0a[4] = {w0v.x, w0v.y, w0v.z, w0v.w};
                const float w1a[4] = {w1v.x, w1v.y, w1v.z, w1v.w};
#pragma unroll
                for (int j = 0; j < 4; ++j)
#pragma unroll
                    for (int i = 0; i < 4; ++i)
                        acc[j][i] += av[j][kk] * w0a[i] + tv[j][kk] * w1a[i];
            }
        }

#pragma unroll
        for (int j = 0; j < 4; ++j) {
            float4 o;
            float* oo = (float*)&o;
#pragma unroll
            for (int i = 0; i < 4; ++i) {
                float v = acc[j][i] > 0.0f ? acc[j][i] : 0.0f;
                if (combine) v = 0.5f * (as[r0 + j][c0 + i] + v);
                oo[i] = v;
            }
            *(float4*)(out + (rb + r0 + j) * NF + c0) = o;
        }
    }
}

extern "C" void kernel_launch(void* const* d_in, const int* in_sizes, int n_in,
                              void* d_out, int out_size, void* d_ws, size_t ws_size,
                              hipStream_t stream) {
    const float* x   = (const float*)d_in[0];
    const int*   ei  = (const int*)d_in[1];
    const float* W01 = (const float*)d_in[2];
    const float* W11 = (const float*)d_in[3];
    const float* b1  = (const float*)d_in[4];
    const float* W02 = (const float*)d_in[5];
    const float* W12 = (const float*)d_in[6];
    const float* b2  = (const float*)d_in[7];
    float* out = (float*)d_out;

    const int* row = ei;        // edge_index[0]
    const int* col = ei + NE;   // edge_index[1]

    // ws layout (bytes):
    //   deg    @ 0         (400000)
    //   dinv   @ 400000    (400000)
    //   offs   @ 800000    (400016, NN+1 ints padded)
    //   cursor @ 1200016   (400000)
    //   ccol   @ 1600016   (6400000)  [16B aligned]
    //   tx     @ 8000016   (51200000) [16B aligned]
    //   bsum   @ 59200016  (NBLK ints)
    char* ws = (char*)d_ws;
    int*   deg    = (int*)(ws);
    float* dinv   = (float*)(ws + 400000);
    int*   offs   = (int*)(ws + 800000);
    int*   cursor = (int*)(ws + 1200016);
    int*   ccol   = (int*)(ws + 1600016);
    float* tx     = (float*)(ws + 8000016);
    int*   bsum   = (int*)(ws + 59200016);

    hipMemsetAsync(deg, 0, (size_t)NN * sizeof(int), stream);

    k_deg    <<<NE / 256, 256, 0, stream>>>(row, deg);
    k_dinv   <<<NBLK, 256, 0, stream>>>(deg, dinv);
    k_scan1  <<<NBLK, 256, 0, stream>>>(deg, bsum);
    k_scan2  <<<1, 256, 0, stream>>>(bsum);
    k_scan3  <<<NBLK, 256, 0, stream>>>(deg, bsum, offs, cursor);
    k_scatter<<<NE / 256, 256, 0, stream>>>(row, col, cursor, ccol);

    const int gatherBlocks = (NN * 64 + 255) / 256;  // 1 wave per row

    // layer 1
    k_gather<<<gatherBlocks, 256, 0, stream>>>(offs, ccol, dinv, x, tx);
    k_gemm  <<<256, 256, 0, stream>>>(x, tx, W01, W11, b1, out, 0);

    // layer 2 (x1 lives in d_out; block-disjoint rows make in-place safe)
    k_gather<<<gatherBlocks, 256, 0, stream>>>(offs, ccol, dinv, out, tx);
    k_gemm  <<<256, 256, 0, stream>>>(out, tx, W02, W12, b2, out, 1);
}

// Round 4
// 460.991 us; speedup vs baseline: 12.6518x; 1.6794x over previous
//
#include <hip/hip_runtime.h>

#define NN 100000
#define NE 1600000
#define NF 128
#define NSTRIP (NN / 16)              // 6250 16-row strips
#define NBLK ((NN + 255) / 256)       // 391 scan blocks

typedef __attribute__((ext_vector_type(8))) short short8;   // 8 bf16 (4 VGPRs)
typedef __attribute__((ext_vector_type(4))) float f32x4;    // MFMA accumulator

__device__ __forceinline__ unsigned short f2b(float f) {
    union { float f; unsigned int u; } v; v.f = f;
    unsigned int u = v.u;
    unsigned int r = (u + 0x7fffu + ((u >> 16) & 1u)) >> 16;   // RNE
    return (unsigned short)r;
}
__device__ __forceinline__ float b2f(unsigned short b) {
    return __uint_as_float(((unsigned int)b) << 16);
}

// ---------------- degree count (int atomics) ----------------
__global__ __launch_bounds__(256) void k_deg(const int* __restrict__ row,
                                             int* __restrict__ deg) {
    int e = blockIdx.x * 256 + threadIdx.x;
    if (e < NE) atomicAdd(deg + row[e], 1);
}

// ---------------- dinv = deg>0 ? rsqrt(deg) : 0 ----------------
__global__ __launch_bounds__(256) void k_dinv(const int* __restrict__ deg,
                                              float* __restrict__ dinv) {
    int i = blockIdx.x * 256 + threadIdx.x;
    if (i < NN) {
        int d = deg[i];
        dinv[i] = d > 0 ? rsqrtf((float)d) : 0.0f;
    }
}

// ---------------- scan phase 1: per-block sums ----------------
__global__ __launch_bounds__(256) void k_scan1(const int* __restrict__ deg,
                                               int* __restrict__ bsum) {
    __shared__ int s[256];
    int t = threadIdx.x;
    int i = blockIdx.x * 256 + t;
    s[t] = i < NN ? deg[i] : 0;
    __syncthreads();
    for (int off = 128; off > 0; off >>= 1) {
        if (t < off) s[t] += s[t + off];
        __syncthreads();
    }
    if (t == 0) bsum[blockIdx.x] = s[0];
}

// ---------------- scan phase 2: exclusive scan of block sums ----------------
__global__ __launch_bounds__(256) void k_scan2(int* __restrict__ bsum) {
    __shared__ int s[NBLK];
    int t = threadIdx.x;
    for (int i = t; i < NBLK; i += 256) s[i] = bsum[i];
    __syncthreads();
    if (t == 0) {
        int run = 0;
        for (int i = 0; i < NBLK; ++i) { int v = s[i]; s[i] = run; run += v; }
    }
    __syncthreads();
    for (int i = t; i < NBLK; i += 256) bsum[i] = s[i];
}

// ---------------- scan phase 3: block-local scan + base -> offs, cursor -----
__global__ __launch_bounds__(256) void k_scan3(const int* __restrict__ deg,
                                               const int* __restrict__ bsum,
                                               int* __restrict__ offs,
                                               int* __restrict__ cursor) {
    __shared__ int s[256];
    int t = threadIdx.x;
    int i = blockIdx.x * 256 + t;
    int v = i < NN ? deg[i] : 0;
    s[t] = v;
    __syncthreads();
    for (int off = 1; off < 256; off <<= 1) {
        int u = (t >= off) ? s[t - off] : 0;
        __syncthreads();
        s[t] += u;
        __syncthreads();
    }
    int pos = bsum[blockIdx.x] + s[t] - v;          // exclusive
    if (i < NN) { offs[i] = pos; cursor[i] = pos; }
    if (i == 0) offs[NN] = NE;
}

// ---------------- scatter cols into CSR slots ----------------
__global__ __launch_bounds__(256) void k_scatter(const int* __restrict__ row,
                                                 const int* __restrict__ col,
                                                 int* __restrict__ cursor,
                                                 int* __restrict__ ccol) {
    int e = blockIdx.x * 256 + threadIdx.x;
    if (e < NE) {
        int pos = atomicAdd(cursor + row[e], 1);
        ccol[pos] = col[e];
    }
}

// ---------------- fp32 -> bf16 row-major convert (x) ----------------
__global__ __launch_bounds__(256) void k_cvt(const float* __restrict__ x,
                                             unsigned int* __restrict__ xb) {
    int i = blockIdx.x * 256 + threadIdx.x;           // uint2 (4 elem) granules
    float4 v = ((const float4*)x)[i];
    uint2 o;
    o.x = (unsigned int)f2b(v.x) | ((unsigned int)f2b(v.y) << 16);
    o.y = (unsigned int)f2b(v.z) | ((unsigned int)f2b(v.w) << 16);
    ((uint2*)xb)[i] = o;
}

// ---------------- pack 4 weight matrices into MFMA B-fragment order ---------
// WP[mi][ ((kt*4+g)*128 + n)*8 + j ] = bf16(W[k][n]),  k = kt*32 + g*8 + j
__global__ __launch_bounds__(256) void k_pack(const float* __restrict__ W01,
                                              const float* __restrict__ W11,
                                              const float* __restrict__ W02,
                                              const float* __restrict__ W12,
                                              unsigned short* __restrict__ WP) {
    int idx = blockIdx.x * 256 + threadIdx.x;         // 4 * 16384
    int mi = idx >> 14;
    int e = idx & 16383;
    const float* W = mi == 0 ? W01 : mi == 1 ? W11 : mi == 2 ? W02 : W12;
    int k = e >> 7, n = e & 127;
    int kt = k >> 5, g = (k >> 3) & 3, j = k & 7;
    WP[mi * 16384 + (((kt * 4 + g) * 128 + n) << 3) + j] = f2b(W[e]);
}

// ---------------- gather SpMM (bf16 in/out, fp32 accumulate) ----------------
// one 64-lane wave per row; lane owns 2 feats (1 uint = 2 bf16).
__global__ __launch_bounds__(256) void k_gather(const int* __restrict__ offs,
                                                const int* __restrict__ ccol,
                                                const float* __restrict__ dinv,
                                                const unsigned int* __restrict__ xb,
                                                unsigned int* __restrict__ txb) {
    int r = (blockIdx.x * 256 + threadIdx.x) >> 6;
    if (r >= NN) return;
    int lane = threadIdx.x & 63;
    int beg = offs[r], end = offs[r + 1];
    float ax = 0.0f, ay = 0.0f;
    int j = beg;
    for (; j + 3 < end; j += 4) {
        int c0 = ccol[j], c1 = ccol[j + 1], c2 = ccol[j + 2], c3 = ccol[j + 3];
        float w0 = dinv[c0], w1 = dinv[c1], w2 = dinv[c2], w3 = dinv[c3];
        unsigned int u0 = xb[c0 * 64 + lane];
        unsigned int u1 = xb[c1 * 64 + lane];
        unsigned int u2 = xb[c2 * 64 + lane];
        unsigned int u3 = xb[c3 * 64 + lane];
        ax += w0 * __uint_as_float(u0 << 16) + w1 * __uint_as_float(u1 << 16)
            + w2 * __uint_as_float(u2 << 16) + w3 * __uint_as_float(u3 << 16);
        ay += w0 * __uint_as_float(u0 & 0xffff0000u) + w1 * __uint_as_float(u1 & 0xffff0000u)
            + w2 * __uint_as_float(u2 & 0xffff0000u) + w3 * __uint_as_float(u3 & 0xffff0000u);
    }
    for (; j < end; ++j) {
        int c = ccol[j];
        float w = dinv[c];
        unsigned int u = xb[c * 64 + lane];
        ax += w * __uint_as_float(u << 16);
        ay += w * __uint_as_float(u & 0xffff0000u);
    }
    float s = -dinv[r];
    txb[r * 64 + lane] = (unsigned int)f2b(s * ax) | ((unsigned int)f2b(s * ay) << 16);
}

// ---------------- MFMA dual-GEMM: relu(A@W0 + T@W1 + b) ----------------
// One wave per 16-row strip, full 128-col width, no LDS.
// mode 0: write bf16 result to Aout (= x1 for layer 2)
// mode 1: out = 0.5*(x1_bf16 + relu(acc))  -> fp32 d_out
__global__ __launch_bounds__(256) void k_mm(const unsigned short* __restrict__ Abf,
                                            const unsigned short* __restrict__ Tbf,
                                            const unsigned short* __restrict__ WP0,
                                            const unsigned short* __restrict__ WP1,
                                            const float* __restrict__ bias,
                                            float* __restrict__ out,
                                            unsigned short* __restrict__ Aout,
                                            int mode) {
    int wid = (blockIdx.x * 256 + threadIdx.x) >> 6;
    if (wid >= NSTRIP) return;
    int lane = threadIdx.x & 63;
    int g = lane >> 4, m = lane & 15;

    const short8* Afr = (const short8*)(Abf + (size_t)(wid * 16 + m) * NF + g * 8);
    const short8* Tfr = (const short8*)(Tbf + (size_t)(wid * 16 + m) * NF + g * 8);
    short8 a[4], t[4];
#pragma unroll
    for (int kt = 0; kt < 4; ++kt) { a[kt] = Afr[kt * 4]; t[kt] = Tfr[kt * 4]; }

    const short8* B0 = (const short8*)WP0 + g * 128 + m;   // + kt*512 + nt*16
    const short8* B1 = (const short8*)WP1 + g * 128 + m;

    f32x4 acc[8];
#pragma unroll
    for (int nt = 0; nt < 8; ++nt) {
        float b = bias[nt * 16 + m];
        acc[nt][0] = b; acc[nt][1] = b; acc[nt][2] = b; acc[nt][3] = b;
    }

#pragma unroll
    for (int nt = 0; nt < 8; ++nt) {
#pragma unroll
        for (int kt = 0; kt < 4; ++kt) {
            acc[nt] = __builtin_amdgcn_mfma_f32_16x16x32_bf16(a[kt], B0[kt * 512 + nt * 16], acc[nt], 0, 0, 0);
            acc[nt] = __builtin_amdgcn_mfma_f32_16x16x32_bf16(t[kt], B1[kt * 512 + nt * 16], acc[nt], 0, 0, 0);
        }
    }

    // epilogue: D col = lane&15, row = (lane>>4)*4 + reg
    int rbase = wid * 16 + g * 4;
#pragma unroll
    for (int nt = 0; nt < 8; ++nt) {
        int c = nt * 16 + m;
#pragma unroll
        for (int r = 0; r < 4; ++r) {
            float v = acc[nt][r];
            v = v > 0.0f ? v : 0.0f;
            size_t o = (size_t)(rbase + r) * NF + c;
            if (mode == 0) {
                Aout[o] = f2b(v);
            } else {
                out[o] = 0.5f * (b2f(Abf[o]) + v);
            }
        }
    }
}

extern "C" void kernel_launch(void* const* d_in, const int* in_sizes, int n_in,
                              void* d_out, int out_size, void* d_ws, size_t ws_size,
                              hipStream_t stream) {
    const float* x   = (const float*)d_in[0];
    const int*   ei  = (const int*)d_in[1];
    const float* W01 = (const float*)d_in[2];
    const float* W11 = (const float*)d_in[3];
    const float* b1  = (const float*)d_in[4];
    const float* W02 = (const float*)d_in[5];
    const float* W12 = (const float*)d_in[6];
    const float* b2  = (const float*)d_in[7];
    float* out = (float*)d_out;

    const int* row = ei;        // edge_index[0]
    const int* col = ei + NE;   // edge_index[1]

    // ws layout (bytes):
    //   deg    @ 0         (400000)
    //   dinv   @ 400000    (400000)
    //   offs   @ 800000    (400016)
    //   cursor @ 1200016   (400000)
    //   bsum   @ 1600016   (1564, pad to 1601584)
    //   WP     @ 1601584   (4 x 32768 = 131072)
    //   ccol   @ 1732656   (6400000)
    //   xbf    @ 8132656   (25600000)   bf16 x, later bf16 x1 (in-place safe)
    //   txbf   @ 33732656  (25600000)   bf16 L_hat x
    char* ws = (char*)d_ws;
    int*            deg    = (int*)(ws);
    float*          dinv   = (float*)(ws + 400000);
    int*            offs   = (int*)(ws + 800000);
    int*            cursor = (int*)(ws + 1200016);
    int*            bsum   = (int*)(ws + 1600016);
    unsigned short* WP     = (unsigned short*)(ws + 1601584);
    int*            ccol   = (int*)(ws + 1732656);
    unsigned short* xbf    = (unsigned short*)(ws + 8132656);
    unsigned short* txbf   = (unsigned short*)(ws + 33732656);

    unsigned short* WP01 = WP;
    unsigned short* WP11 = WP + 16384;
    unsigned short* WP02 = WP + 32768;
    unsigned short* WP12 = WP + 49152;

    hipMemsetAsync(deg, 0, (size_t)NN * sizeof(int), stream);

    k_deg    <<<NE / 256, 256, 0, stream>>>(row, deg);
    k_dinv   <<<NBLK, 256, 0, stream>>>(deg, dinv);
    k_scan1  <<<NBLK, 256, 0, stream>>>(deg, bsum);
    k_scan2  <<<1, 256, 0, stream>>>(bsum);
    k_scan3  <<<NBLK, 256, 0, stream>>>(deg, bsum, offs, cursor);
    k_scatter<<<NE / 256, 256, 0, stream>>>(row, col, cursor, ccol);
    k_cvt    <<<(NN * NF / 4) / 256, 256, 0, stream>>>(x, (unsigned int*)xbf);
    k_pack   <<<(4 * 16384) / 256, 256, 0, stream>>>(W01, W11, W02, W12, WP);

    const int gatherBlocks = (NN * 64) / 256;          // 1 wave per row
    const int mmBlocks = (NSTRIP * 64 + 255) / 256;    // 1 wave per 16-row strip

    // layer 1: tx = L_hat x ; x1_bf = bf16(relu(x@W0 + tx@W1 + b1)) -> xbf
    k_gather<<<gatherBlocks, 256, 0, stream>>>(offs, ccol, dinv, (const unsigned int*)xbf, (unsigned int*)txbf);
    k_mm    <<<mmBlocks, 256, 0, stream>>>(xbf, txbf, WP01, WP11, b1, out, xbf, 0);

    // layer 2: tx = L_hat x1 ; out = 0.5*(x1 + relu(x1@W0 + tx@W1 + b2))
    k_gather<<<gatherBlocks, 256, 0, stream>>>(offs, ccol, dinv, (const unsigned int*)xbf, (unsigned int*)txbf);
    k_mm    <<<mmBlocks, 256, 0, stream>>>(xbf, txbf, WP02, WP12, b2, out, xbf, 1);
}

// Round 5
// 308.548 us; speedup vs baseline: 18.9027x; 1.4941x over previous
//
#include <hip/hip_runtime.h>

#define NN 100000
#define NE 1600000
#define NF 128
#define NSTRIP (NN / 16)                  // 6250 16-row strips
#define NBUCK ((NN + 127) / 128)          // 782 row-buckets (128 rows each)
#define CAP 2560                          // slab capacity per bucket (mean 2046, +11 sigma)
#define CHUNK 4096                        // edges per k_bin block

typedef __attribute__((ext_vector_type(8))) short short8;   // 8 bf16 (4 VGPRs)
typedef __attribute__((ext_vector_type(4))) float f32x4;    // MFMA accumulator

__device__ __forceinline__ unsigned short f2b(float f) {
    union { float f; unsigned int u; } v; v.f = f;
    unsigned int u = v.u;
    unsigned int r = (u + 0x7fffu + ((u >> 16) & 1u)) >> 16;   // RNE
    return (unsigned short)r;
}
__device__ __forceinline__ float b2f(unsigned short b) {
    return __uint_as_float(((unsigned int)b) << 16);
}

// ---------------- init bucket cursors to slab bases ----------------
__global__ __launch_bounds__(256) void k_init(int* __restrict__ gcur) {
    int i = blockIdx.x * 256 + threadIdx.x;
    if (i < NBUCK) gcur[i] = i * CAP;
}

// ---------------- phase A: LDS-binned bucket scatter ----------------
// Packs (row&127)<<17 | col into per-bucket slabs, bucket = row>>7.
__global__ __launch_bounds__(256) void k_bin(const int* __restrict__ row,
                                             const int* __restrict__ col,
                                             int* __restrict__ gcur,
                                             unsigned int* __restrict__ gslab) {
    __shared__ int hist[NBUCK];
    __shared__ int start[NBUCK];
    __shared__ int gbase[NBUCK];
    __shared__ int scanbuf[256];
    __shared__ unsigned int stage[CHUNK];
    __shared__ unsigned short sb[CHUNK];

    const int t = threadIdx.x;
    const int e0 = blockIdx.x * CHUNK;
    const int cnt = min(CHUNK, NE - e0);

    for (int i = t; i < NBUCK; i += 256) hist[i] = 0;
    __syncthreads();
    for (int i = t; i < cnt; i += 256) atomicAdd(&hist[row[e0 + i] >> 7], 1);
    __syncthreads();

    // block exclusive scan of hist -> start (4 buckets per thread)
    const int b0 = t * 4;
    int s = 0;
#pragma unroll
    for (int k = 0; k < 4; ++k) { int idx = b0 + k; if (idx < NBUCK) s += hist[idx]; }
    scanbuf[t] = s;
    __syncthreads();
    for (int off = 1; off < 256; off <<= 1) {
        int u = t >= off ? scanbuf[t - off] : 0;
        __syncthreads();
        scanbuf[t] += u;
        __syncthreads();
    }
    int run = t > 0 ? scanbuf[t - 1] : 0;
#pragma unroll
    for (int k = 0; k < 4; ++k) {
        int idx = b0 + k;
        if (idx < NBUCK) { start[idx] = run; run += hist[idx]; }
    }
    __syncthreads();

    // reserve global slab space; convert hist into running LDS cursor
    for (int i = t; i < NBUCK; i += 256) {
        int c = hist[i];
        gbase[i] = c > 0 ? atomicAdd(&gcur[i], c) : 0;
        hist[i] = start[i];
    }
    __syncthreads();

    // scatter edges into LDS stage, bucket-ordered
    for (int i = t; i < cnt; i += 256) {
        int r = row[e0 + i];
        int b = r >> 7;
        int p = atomicAdd(&hist[b], 1);
        stage[p] = (unsigned int)col[e0 + i] | ((unsigned int)(r & 127) << 17);
        sb[p] = (unsigned short)b;
    }
    __syncthreads();

    // flush: consecutive i in the same bucket -> consecutive global addresses
    for (int i = t; i < cnt; i += 256) {
        int b = sb[i];
        gslab[gbase[b] + (i - start[b])] = stage[i];
    }
}

// ---------------- tiny scan of bucket counts -> CSR bucket bases ----------------
__global__ __launch_bounds__(256) void k_bscan(const int* __restrict__ gcur,
                                               int* __restrict__ bbase) {
    __shared__ int s[NBUCK];
    int t = threadIdx.x;
    for (int i = t; i < NBUCK; i += 256) s[i] = gcur[i] - i * CAP;
    __syncthreads();
    if (t == 0) {
        int run = 0;
        for (int i = 0; i < NBUCK; ++i) { int v = s[i]; s[i] = run; run += v; }
    }
    __syncthreads();
    for (int i = t; i < NBUCK; i += 256) bbase[i] = s[i];
}

// ---------------- phase B: per-bucket LDS counting sort -> offs, ccol, dinv ----
__global__ __launch_bounds__(256) void k_csr(const unsigned int* __restrict__ gslab,
                                             const int* __restrict__ gcur,
                                             const int* __restrict__ bbase,
                                             int* __restrict__ offs,
                                             int* __restrict__ ccol,
                                             float* __restrict__ dinv) {
    __shared__ int rh[128];
    __shared__ int rcur[128];
    __shared__ unsigned int scol[CAP];

    const int b = blockIdx.x;
    const int segbase = b * CAP;
    const int cnt = gcur[b] - segbase;
    const int csr0 = bbase[b];
    const int t = threadIdx.x;

    if (t < 128) rh[t] = 0;
    __syncthreads();
    for (int i = t; i < cnt; i += 256) atomicAdd(&rh[gslab[segbase + i] >> 17], 1);
    __syncthreads();
    if (t == 0) {
        int run = 0;
        for (int r = 0; r < 128; ++r) { rcur[r] = run; run += rh[r]; }
    }
    __syncthreads();

    const int rbase = b * 128;
    if (t < 128 && rbase + t < NN) {
        offs[rbase + t] = csr0 + rcur[t];
        int d = rh[t];
        dinv[rbase + t] = d > 0 ? rsqrtf((float)d) : 0.0f;
    }
    if (b == NBUCK - 1 && t == 0) offs[NN] = NE;
    __syncthreads();

    for (int i = t; i < cnt; i += 256) {
        unsigned int v = gslab[segbase + i];
        int p = atomicAdd(&rcur[v >> 17], 1);
        scol[p] = v & 0x1ffff;
    }
    __syncthreads();
    for (int i = t; i < cnt; i += 256) ccol[csr0 + i] = scol[i];
}

// ---------------- fp32 -> bf16 row-major convert (x) ----------------
__global__ __launch_bounds__(256) void k_cvt(const float* __restrict__ x,
                                             unsigned int* __restrict__ xb) {
    int i = blockIdx.x * 256 + threadIdx.x;           // uint2 (4 elem) granules
    float4 v = ((const float4*)x)[i];
    uint2 o;
    o.x = (unsigned int)f2b(v.x) | ((unsigned int)f2b(v.y) << 16);
    o.y = (unsigned int)f2b(v.z) | ((unsigned int)f2b(v.w) << 16);
    ((uint2*)xb)[i] = o;
}

// ---------------- pack 4 weight matrices into MFMA B-fragment order ---------
// WP[mi][ ((kt*4+g)*128 + n)*8 + j ] = bf16(W[k][n]),  k = kt*32 + g*8 + j
__global__ __launch_bounds__(256) void k_pack(const float* __restrict__ W01,
                                              const float* __restrict__ W11,
                                              const float* __restrict__ W02,
                                              const float* __restrict__ W12,
                                              unsigned short* __restrict__ WP) {
    int idx = blockIdx.x * 256 + threadIdx.x;         // 4 * 16384
    int mi = idx >> 14;
    int e = idx & 16383;
    const float* W = mi == 0 ? W01 : mi == 1 ? W11 : mi == 2 ? W02 : W12;
    int k = e >> 7, n = e & 127;
    int kt = k >> 5, g = (k >> 3) & 3, j = k & 7;
    WP[mi * 16384 + (((kt * 4 + g) * 128 + n) << 3) + j] = f2b(W[e]);
}

// ---------------- gather SpMM (bf16 in/out, fp32 accumulate) ----------------
__global__ __launch_bounds__(256) void k_gather(const int* __restrict__ offs,
                                                const int* __restrict__ ccol,
                                                const float* __restrict__ dinv,
                                                const unsigned int* __restrict__ xb,
                                                unsigned int* __restrict__ txb) {
    int r = (blockIdx.x * 256 + threadIdx.x) >> 6;
    if (r >= NN) return;
    int lane = threadIdx.x & 63;
    int beg = offs[r], end = offs[r + 1];
    float ax = 0.0f, ay = 0.0f;
    int j = beg;
    for (; j + 3 < end; j += 4) {
        int c0 = ccol[j], c1 = ccol[j + 1], c2 = ccol[j + 2], c3 = ccol[j + 3];
        float w0 = dinv[c0], w1 = dinv[c1], w2 = dinv[c2], w3 = dinv[c3];
        unsigned int u0 = xb[c0 * 64 + lane];
        unsigned int u1 = xb[c1 * 64 + lane];
        unsigned int u2 = xb[c2 * 64 + lane];
        unsigned int u3 = xb[c3 * 64 + lane];
        ax += w0 * __uint_as_float(u0 << 16) + w1 * __uint_as_float(u1 << 16)
            + w2 * __uint_as_float(u2 << 16) + w3 * __uint_as_float(u3 << 16);
        ay += w0 * __uint_as_float(u0 & 0xffff0000u) + w1 * __uint_as_float(u1 & 0xffff0000u)
            + w2 * __uint_as_float(u2 & 0xffff0000u) + w3 * __uint_as_float(u3 & 0xffff0000u);
    }
    for (; j < end; ++j) {
        int c = ccol[j];
        float w = dinv[c];
        unsigned int u = xb[c * 64 + lane];
        ax += w * __uint_as_float(u << 16);
        ay += w * __uint_as_float(u & 0xffff0000u);
    }
    float s = -dinv[r];
    txb[r * 64 + lane] = (unsigned int)f2b(s * ax) | ((unsigned int)f2b(s * ay) << 16);
}

// ---------------- MFMA dual-GEMM: relu(A@W0 + T@W1 + b) ----------------
__global__ __launch_bounds__(256) void k_mm(const unsigned short* __restrict__ Abf,
                                            const unsigned short* __restrict__ Tbf,
                                            const unsigned short* __restrict__ WP0,
                                            const unsigned short* __restrict__ WP1,
                                            const float* __restrict__ bias,
                                            float* __restrict__ out,
                                            unsigned short* __restrict__ Aout,
                                            int mode) {
    int wid = (blockIdx.x * 256 + threadIdx.x) >> 6;
    if (wid >= NSTRIP) return;
    int lane = threadIdx.x & 63;
    int g = lane >> 4, m = lane & 15;

    const short8* Afr = (const short8*)(Abf + (size_t)(wid * 16 + m) * NF + g * 8);
    const short8* Tfr = (const short8*)(Tbf + (size_t)(wid * 16 + m) * NF + g * 8);
    short8 a[4], t[4];
#pragma unroll
    for (int kt = 0; kt < 4; ++kt) { a[kt] = Afr[kt * 4]; t[kt] = Tfr[kt * 4]; }

    const short8* B0 = (const short8*)WP0 + g * 128 + m;   // + kt*512 + nt*16
    const short8* B1 = (const short8*)WP1 + g * 128 + m;

    f32x4 acc[8];
#pragma unroll
    for (int nt = 0; nt < 8; ++nt) {
        float b = bias[nt * 16 + m];
        acc[nt][0] = b; acc[nt][1] = b; acc[nt][2] = b; acc[nt][3] = b;
    }

#pragma unroll
    for (int nt = 0; nt < 8; ++nt) {
#pragma unroll
        for (int kt = 0; kt < 4; ++kt) {
            acc[nt] = __builtin_amdgcn_mfma_f32_16x16x32_bf16(a[kt], B0[kt * 512 + nt * 16], acc[nt], 0, 0, 0);
            acc[nt] = __builtin_amdgcn_mfma_f32_16x16x32_bf16(t[kt], B1[kt * 512 + nt * 16], acc[nt], 0, 0, 0);
        }
    }

    int rbase = wid * 16 + g * 4;
#pragma unroll
    for (int nt = 0; nt < 8; ++nt) {
        int c = nt * 16 + m;
#pragma unroll
        for (int r = 0; r < 4; ++r) {
            float v = acc[nt][r];
            v = v > 0.0f ? v : 0.0f;
            size_t o = (size_t)(rbase + r) * NF + c;
            if (mode == 0) {
                Aout[o] = f2b(v);
            } else {
                out[o] = 0.5f * (b2f(Abf[o]) + v);
            }
        }
    }
}

extern "C" void kernel_launch(void* const* d_in, const int* in_sizes, int n_in,
                              void* d_out, int out_size, void* d_ws, size_t ws_size,
                              hipStream_t stream) {
    const float* x   = (const float*)d_in[0];
    const int*   ei  = (const int*)d_in[1];
    const float* W01 = (const float*)d_in[2];
    const float* W11 = (const float*)d_in[3];
    const float* b1  = (const float*)d_in[4];
    const float* W02 = (const float*)d_in[5];
    const float* W12 = (const float*)d_in[6];
    const float* b2  = (const float*)d_in[7];
    float* out = (float*)d_out;

    const int* row = ei;        // edge_index[0]
    const int* col = ei + NE;   // edge_index[1]

    // ws layout (bytes):
    //   gcur  @ 0         (3128, pad 3200)
    //   bbase @ 3200      (3128, pad 6400)
    //   dinv  @ 6400      (400000)           -> 406400
    //   offs  @ 406400    (400016)           -> 806416
    //   ccol  @ 806416    (6400000)          -> 7206416
    //   WP    @ 7206416   (131072)           -> 7337488
    //   xbf   @ 7337488   (25600000)         -> 32937488
    //   txbf  @ 32937488  (25600000; gslab 8007680 overlays — consumed before gather)
    char* ws = (char*)d_ws;
    int*            gcur  = (int*)(ws);
    int*            bbase = (int*)(ws + 3200);
    float*          dinv  = (float*)(ws + 6400);
    int*            offs  = (int*)(ws + 406400);
    int*            ccol  = (int*)(ws + 806416);
    unsigned short* WP    = (unsigned short*)(ws + 7206416);
    unsigned short* xbf   = (unsigned short*)(ws + 7337488);
    unsigned short* txbf  = (unsigned short*)(ws + 32937488);
    unsigned int*   gslab = (unsigned int*)(ws + 32937488);   // overlay, pre-gather only

    unsigned short* WP01 = WP;
    unsigned short* WP11 = WP + 16384;
    unsigned short* WP02 = WP + 32768;
    unsigned short* WP12 = WP + 49152;

    // CSR build (bucket sort, no global scatter amplification)
    k_init <<<(NBUCK + 255) / 256, 256, 0, stream>>>(gcur);
    k_bin  <<<(NE + CHUNK - 1) / CHUNK, 256, 0, stream>>>(row, col, gcur, gslab);
    k_bscan<<<1, 256, 0, stream>>>(gcur, bbase);
    k_csr  <<<NBUCK, 256, 0, stream>>>(gslab, gcur, bbase, offs, ccol, dinv);

    k_cvt  <<<(NN * NF / 4) / 256, 256, 0, stream>>>(x, (unsigned int*)xbf);
    k_pack <<<(4 * 16384) / 256, 256, 0, stream>>>(W01, W11, W02, W12, WP);

    const int gatherBlocks = (NN * 64) / 256;          // 1 wave per row
    const int mmBlocks = (NSTRIP * 64 + 255) / 256;    // 1 wave per 16-row strip

    // layer 1: tx = L_hat x ; x1_bf = bf16(relu(x@W0 + tx@W1 + b1)) -> xbf
    k_gather<<<gatherBlocks, 256, 0, stream>>>(offs, ccol, dinv, (const unsigned int*)xbf, (unsigned int*)txbf);
    k_mm    <<<mmBlocks, 256, 0, stream>>>(xbf, txbf, WP01, WP11, b1, out, xbf, 0);

    // layer 2: tx = L_hat x1 ; out = 0.5*(x1 + relu(x1@W0 + tx@W1 + b2))
    k_gather<<<gatherBlocks, 256, 0, stream>>>(offs, ccol, dinv, (const unsigned int*)xbf, (unsigned int*)txbf);
    k_mm    <<<mmBlocks, 256, 0, stream>>>(xbf, txbf, WP02, WP12, b2, out, xbf, 1);
}

// Round 7
// 277.069 us; speedup vs baseline: 21.0503x; 1.1136x over previous
//
#include <hip/hip_runtime.h>

#define NN 100000
#define NE 1600000
#define NF 128
#define NSTRIP (NN / 16)                  // 6250 16-row strips
#define NBUCK ((NN + 127) / 128)          // 782 row-buckets (128 rows each)
#define CAP 2560                          // slab capacity per bucket (mean 2046, +11 sigma)
#define CHUNK 4096                        // edges per k_bin block

typedef __attribute__((ext_vector_type(8))) short short8;   // 8 bf16 (4 VGPRs)
typedef __attribute__((ext_vector_type(4))) float f32x4;    // MFMA accumulator

__device__ __forceinline__ unsigned short f2b(float f) {
    union { float f; unsigned int u; } v; v.f = f;
    unsigned int u = v.u;
    unsigned int r = (u + 0x7fffu + ((u >> 16) & 1u)) >> 16;   // RNE
    return (unsigned short)r;
}
__device__ __forceinline__ float b2f(unsigned short b) {
    return __uint_as_float(((unsigned int)b) << 16);
}

// ---------------- init bucket cursors to slab bases ----------------
__global__ __launch_bounds__(256) void k_init(int* __restrict__ gcur) {
    int i = blockIdx.x * 256 + threadIdx.x;
    if (i < NBUCK) gcur[i] = i * CAP;
}

// ---------------- phase A: LDS-binned bucket scatter ----------------
__global__ __launch_bounds__(256) void k_bin(const int* __restrict__ row,
                                             const int* __restrict__ col,
                                             int* __restrict__ gcur,
                                             unsigned int* __restrict__ gslab) {
    __shared__ int hist[NBUCK];
    __shared__ int start[NBUCK];
    __shared__ int gbase[NBUCK];
    __shared__ int scanbuf[256];
    __shared__ unsigned int stage[CHUNK];
    __shared__ unsigned short sb[CHUNK];

    const int t = threadIdx.x;
    const int e0 = blockIdx.x * CHUNK;
    const int cnt = min(CHUNK, NE - e0);

    for (int i = t; i < NBUCK; i += 256) hist[i] = 0;
    __syncthreads();
    for (int i = t; i < cnt; i += 256) atomicAdd(&hist[row[e0 + i] >> 7], 1);
    __syncthreads();

    const int b0 = t * 4;
    int s = 0;
#pragma unroll
    for (int k = 0; k < 4; ++k) { int idx = b0 + k; if (idx < NBUCK) s += hist[idx]; }
    scanbuf[t] = s;
    __syncthreads();
    for (int off = 1; off < 256; off <<= 1) {
        int u = t >= off ? scanbuf[t - off] : 0;
        __syncthreads();
        scanbuf[t] += u;
        __syncthreads();
    }
    int run = t > 0 ? scanbuf[t - 1] : 0;
#pragma unroll
    for (int k = 0; k < 4; ++k) {
        int idx = b0 + k;
        if (idx < NBUCK) { start[idx] = run; run += hist[idx]; }
    }
    __syncthreads();

    for (int i = t; i < NBUCK; i += 256) {
        int c = hist[i];
        gbase[i] = c > 0 ? atomicAdd(&gcur[i], c) : 0;
        hist[i] = start[i];
    }
    __syncthreads();

    for (int i = t; i < cnt; i += 256) {
        int r = row[e0 + i];
        int b = r >> 7;
        int p = atomicAdd(&hist[b], 1);
        stage[p] = (unsigned int)col[e0 + i] | ((unsigned int)(r & 127) << 17);
        sb[p] = (unsigned short)b;
    }
    __syncthreads();

    for (int i = t; i < cnt; i += 256) {
        int b = sb[i];
        gslab[gbase[b] + (i - start[b])] = stage[i];
    }
}

// ---------------- tiny scan of bucket counts -> CSR bucket bases ----------------
__global__ __launch_bounds__(256) void k_bscan(const int* __restrict__ gcur,
                                               int* __restrict__ bbase) {
    __shared__ int s[NBUCK];
    int t = threadIdx.x;
    for (int i = t; i < NBUCK; i += 256) s[i] = gcur[i] - i * CAP;
    __syncthreads();
    if (t == 0) {
        int run = 0;
        for (int i = 0; i < NBUCK; ++i) { int v = s[i]; s[i] = run; run += v; }
    }
    __syncthreads();
    for (int i = t; i < NBUCK; i += 256) bbase[i] = s[i];
}

// ---------------- phase B: per-bucket LDS counting sort -> offs, ccol, dinv ----
__global__ __launch_bounds__(256) void k_csr(const unsigned int* __restrict__ gslab,
                                             const int* __restrict__ gcur,
                                             const int* __restrict__ bbase,
                                             int* __restrict__ offs,
                                             int* __restrict__ ccol,
                                             float* __restrict__ dinv) {
    __shared__ int rh[128];
    __shared__ int rcur[128];
    __shared__ unsigned int scol[CAP];

    const int b = blockIdx.x;
    const int segbase = b * CAP;
    const int cnt = gcur[b] - segbase;
    const int csr0 = bbase[b];
    const int t = threadIdx.x;

    if (t < 128) rh[t] = 0;
    __syncthreads();
    for (int i = t; i < cnt; i += 256) atomicAdd(&rh[gslab[segbase + i] >> 17], 1);
    __syncthreads();
    if (t == 0) {
        int run = 0;
        for (int r = 0; r < 128; ++r) { rcur[r] = run; run += rh[r]; }
    }
    __syncthreads();

    const int rbase = b * 128;
    if (t < 128 && rbase + t < NN) {
        offs[rbase + t] = csr0 + rcur[t];
        int d = rh[t];
        dinv[rbase + t] = d > 0 ? rsqrtf((float)d) : 0.0f;
    }
    if (b == NBUCK - 1 && t == 0) offs[NN] = NE;
    __syncthreads();

    for (int i = t; i < cnt; i += 256) {
        unsigned int v = gslab[segbase + i];
        int p = atomicAdd(&rcur[v >> 17], 1);
        scol[p] = v & 0x1ffff;
    }
    __syncthreads();
    for (int i = t; i < cnt; i += 256) ccol[csr0 + i] = scol[i];
}

// ---------------- per-node int8 quantization of x (bias 128) + dsc ----------
// one wave per row; lane owns 2 feats.
__global__ __launch_bounds__(256) void k_quant(const float* __restrict__ x,
                                               const float* __restrict__ dinv,
                                               unsigned short* __restrict__ xq,
                                               float* __restrict__ dsc) {
    int r = (blockIdx.x * 256 + threadIdx.x) >> 6;
    int lane = threadIdx.x & 63;
    float2 v = ((const float2*)x)[r * 64 + lane];
    float m = fmaxf(fabsf(v.x), fabsf(v.y));
#pragma unroll
    for (int mask = 32; mask; mask >>= 1) m = fmaxf(m, __shfl_xor(m, mask));
    float s = m * (1.0f / 127.0f);
    float inv = m > 0.0f ? 127.0f / m : 0.0f;
    int qx = (int)rintf(v.x * inv) + 128;
    int qy = (int)rintf(v.y * inv) + 128;
    xq[r * 64 + lane] = (unsigned short)(qx | (qy << 8));
    if (lane == 0) dsc[r] = dinv[r] * s;
}

// ---------------- pack 4 weight matrices into MFMA B-fragment order ---------
// WP[mi][ ((kt*4+g)*128 + n)*8 + j ] = bf16(W[k][n]),  k = kt*32 + g*8 + j
__global__ __launch_bounds__(256) void k_pack(const float* __restrict__ W01,
                                              const float* __restrict__ W11,
                                              const float* __restrict__ W02,
                                              const float* __restrict__ W12,
                                              unsigned short* __restrict__ WP) {
    int idx = blockIdx.x * 256 + threadIdx.x;         // 4 * 16384
    int mi = idx >> 14;
    int e = idx & 16383;
    const float* W = mi == 0 ? W01 : mi == 1 ? W11 : mi == 2 ? W02 : W12;
    int k = e >> 7, n = e & 127;
    int kt = k >> 5, g = (k >> 3) & 3, j = k & 7;
    WP[mi * 16384 + (((kt * 4 + g) * 128 + n) << 3) + j] = f2b(W[e]);
}

// ---------------- gather SpMM (int8 in, bf16 out, fp32 accumulate) ----------
// value_c = s_c*(q - qbias); sum dinv_c*value = sum dsc_c*q - qbias*sum dsc_c
__global__ __launch_bounds__(256) void k_gather(const int* __restrict__ offs,
                                                const int* __restrict__ ccol,
                                                const float* __restrict__ dsc,
                                                const float* __restrict__ dinv,
                                                const unsigned short* __restrict__ xq,
                                                unsigned int* __restrict__ txb,
                                                float qbias) {
    int r = (blockIdx.x * 256 + threadIdx.x) >> 6;
    if (r >= NN) return;
    int lane = threadIdx.x & 63;
    int beg = offs[r], end = offs[r + 1];
    float ax = 0.0f, ay = 0.0f, S = 0.0f;
    int j = beg;
    for (; j + 3 < end; j += 4) {
        int c0 = ccol[j], c1 = ccol[j + 1], c2 = ccol[j + 2], c3 = ccol[j + 3];
        float w0 = dsc[c0], w1 = dsc[c1], w2 = dsc[c2], w3 = dsc[c3];
        unsigned int u0 = xq[c0 * 64 + lane];
        unsigned int u1 = xq[c1 * 64 + lane];
        unsigned int u2 = xq[c2 * 64 + lane];
        unsigned int u3 = xq[c3 * 64 + lane];
        ax += w0 * (float)(u0 & 0xffu) + w1 * (float)(u1 & 0xffu)
            + w2 * (float)(u2 & 0xffu) + w3 * (float)(u3 & 0xffu);
        ay += w0 * (float)(u0 >> 8) + w1 * (float)(u1 >> 8)
            + w2 * (float)(u2 >> 8) + w3 * (float)(u3 >> 8);
        S += w0 + w1 + w2 + w3;
    }
    for (; j < end; ++j) {
        int c = ccol[j];
        float w = dsc[c];
        unsigned int u = xq[c * 64 + lane];
        ax += w * (float)(u & 0xffu);
        ay += w * (float)(u >> 8);
        S += w;
    }
    ax -= qbias * S;
    ay -= qbias * S;
    float s = -dinv[r];
    txb[r * 64 + lane] = (unsigned int)f2b(s * ax) | ((unsigned int)f2b(s * ay) << 16);
}

// ---------------- MFMA dual-GEMM: relu(A@W0 + T@W1 + b) ----------------
// mode 0: A from fp32 x; writes x1 as int8 (bias 0) + dsc/s1.
// mode 1: A from int8 x1 (decode with s1); out = 0.5*(x1 + relu(acc)).
__global__ __launch_bounds__(256) void k_mm(const float* __restrict__ Axf,
                                            const unsigned char* __restrict__ Aq,
                                            const float* __restrict__ s1_in,
                                            const unsigned short* __restrict__ Tbf,
                                            const unsigned short* __restrict__ WP0,
                                            const unsigned short* __restrict__ WP1,
                                            const float* __restrict__ bias,
                                            const float* __restrict__ dinv,
                                            float* __restrict__ out,
                                            unsigned char* __restrict__ Qout,
                                            float* __restrict__ dsc_out,
                                            float* __restrict__ s1_out,
                                            int mode) {
    int wid = (blockIdx.x * 256 + threadIdx.x) >> 6;
    if (wid >= NSTRIP) return;
    int lane = threadIdx.x & 63;
    int g = lane >> 4, m = lane & 15;

    short8 a[4], t[4];
    if (mode == 0) {
        const float* Arow = Axf + (size_t)(wid * 16 + m) * NF + g * 8;
#pragma unroll
        for (int kt = 0; kt < 4; ++kt) {
            float4 f0 = *(const float4*)(Arow + kt * 32);
            float4 f1 = *(const float4*)(Arow + kt * 32 + 4);
            short8 v;
            v[0] = f2b(f0.x); v[1] = f2b(f0.y); v[2] = f2b(f0.z); v[3] = f2b(f0.w);
            v[4] = f2b(f1.x); v[5] = f2b(f1.y); v[6] = f2b(f1.z); v[7] = f2b(f1.w);
            a[kt] = v;
        }
    } else {
        float sA = s1_in[wid * 16 + m];
        const unsigned char* Arow = Aq + (size_t)(wid * 16 + m) * NF + g * 8;
#pragma unroll
        for (int kt = 0; kt < 4; ++kt) {
            uint2 u = *(const uint2*)(Arow + kt * 32);
            short8 v;
            v[0] = f2b(sA * (float)(u.x & 0xffu));
            v[1] = f2b(sA * (float)((u.x >> 8) & 0xffu));
            v[2] = f2b(sA * (float)((u.x >> 16) & 0xffu));
            v[3] = f2b(sA * (float)(u.x >> 24));
            v[4] = f2b(sA * (float)(u.y & 0xffu));
            v[5] = f2b(sA * (float)((u.y >> 8) & 0xffu));
            v[6] = f2b(sA * (float)((u.y >> 16) & 0xffu));
            v[7] = f2b(sA * (float)(u.y >> 24));
            a[kt] = v;
        }
    }

    const short8* Tfr = (const short8*)(Tbf + (size_t)(wid * 16 + m) * NF + g * 8);
#pragma unroll
    for (int kt = 0; kt < 4; ++kt) t[kt] = Tfr[kt * 4];

    const short8* B0 = (const short8*)WP0 + g * 128 + m;   // + kt*512 + nt*16
    const short8* B1 = (const short8*)WP1 + g * 128 + m;

    f32x4 acc[8];
#pragma unroll
    for (int nt = 0; nt < 8; ++nt) {
        float b = bias[nt * 16 + m];
        acc[nt][0] = b; acc[nt][1] = b; acc[nt][2] = b; acc[nt][3] = b;
    }

#pragma unroll
    for (int nt = 0; nt < 8; ++nt) {
#pragma unroll
        for (int kt = 0; kt < 4; ++kt) {
            acc[nt] = __builtin_amdgcn_mfma_f32_16x16x32_bf16(a[kt], B0[kt * 512 + nt * 16], acc[nt], 0, 0, 0);
            acc[nt] = __builtin_amdgcn_mfma_f32_16x16x32_bf16(t[kt], B1[kt * 512 + nt * 16], acc[nt], 0, 0, 0);
        }
    }

    // relu
#pragma unroll
    for (int nt = 0; nt < 8; ++nt)
#pragma unroll
        for (int r = 0; r < 4; ++r) acc[nt][r] = fmaxf(acc[nt][r], 0.0f);

    int rbase = wid * 16 + g * 4;   // D: col = nt*16 + m, row = rbase + r
    if (mode == 0) {
        // per-row max across the 16-lane m-group
        float mr[4] = {0.0f, 0.0f, 0.0f, 0.0f};
#pragma unroll
        for (int nt = 0; nt < 8; ++nt)
#pragma unroll
            for (int r = 0; r < 4; ++r) mr[r] = fmaxf(mr[r], acc[nt][r]);
#pragma unroll
        for (int mask = 1; mask < 16; mask <<= 1)
#pragma unroll
            for (int r = 0; r < 4; ++r) mr[r] = fmaxf(mr[r], __shfl_xor(mr[r], mask));

        float inv[4], s1v[4];
#pragma unroll
        for (int r = 0; r < 4; ++r) {
            s1v[r] = mr[r] * (1.0f / 255.0f);
            inv[r] = mr[r] > 0.0f ? 255.0f / mr[r] : 0.0f;
        }
#pragma unroll
        for (int nt = 0; nt < 8; ++nt) {
            int c = nt * 16 + m;
#pragma unroll
            for (int r = 0; r < 4; ++r) {
                int q = (int)rintf(acc[nt][r] * inv[r]);
                q = q > 255 ? 255 : q;
                Qout[(size_t)(rbase + r) * NF + c] = (unsigned char)q;
            }
        }
        if (m == 0) {
#pragma unroll
            for (int r = 0; r < 4; ++r) {
                s1_out[rbase + r] = s1v[r];
                dsc_out[rbase + r] = dinv[rbase + r] * s1v[r];
            }
        }
    } else {
        float sR[4];
#pragma unroll
        for (int r = 0; r < 4; ++r) sR[r] = s1_in[rbase + r];
#pragma unroll
        for (int nt = 0; nt < 8; ++nt) {
            int c = nt * 16 + m;
#pragma unroll
            for (int r = 0; r < 4; ++r) {
                size_t o = (size_t)(rbase + r) * NF + c;
                float x1v = sR[r] * (float)Aq[o];
                out[o] = 0.5f * (x1v + acc[nt][r]);
            }
        }
    }
}

extern "C" void kernel_launch(void* const* d_in, const int* in_sizes, int n_in,
                              void* d_out, int out_size, void* d_ws, size_t ws_size,
                              hipStream_t stream) {
    const float* x   = (const float*)d_in[0];
    const int*   ei  = (const int*)d_in[1];
    const float* W01 = (const float*)d_in[2];
    const float* W11 = (const float*)d_in[3];
    const float* b1  = (const float*)d_in[4];
    const float* W02 = (const float*)d_in[5];
    const float* W12 = (const float*)d_in[6];
    const float* b2  = (const float*)d_in[7];
    float* out = (float*)d_out;

    const int* row = ei;        // edge_index[0]
    const int* col = ei + NE;   // edge_index[1]

    // ws layout (bytes), total 46,537,488:
    //   gcur  @ 0         (3200)
    //   bbase @ 3200      (3200)      -> 6400
    //   dinv  @ 6400      (400000)    -> 406400
    //   offs  @ 406400    (400016)    -> 806416
    //   ccol  @ 806416    (6400000)   -> 7206416
    //   WP    @ 7206416   (131072)    -> 7337488   (4 bf16 weight frag sets)
    //   dsc   @ 7337488   (400000)    -> 7737488   (dinv*scale, per layer)
    //   s1a   @ 7737488   (400000)    -> 8137488   (x1 per-row scale)
    //   xq    @ 8137488   (12800000)  -> 20937488  (int8 x, then int8 x1)
    //   txb   @ 20937488  (25600000)  -> 46537488  (bf16 tx; gslab overlays pre-gather)
    char* ws = (char*)d_ws;
    int*            gcur  = (int*)(ws);
    int*            bbase = (int*)(ws + 3200);
    float*          dinv  = (float*)(ws + 6400);
    int*            offs  = (int*)(ws + 406400);
    int*            ccol  = (int*)(ws + 806416);
    unsigned short* WP    = (unsigned short*)(ws + 7206416);
    float*          dsc   = (float*)(ws + 7337488);
    float*          s1a   = (float*)(ws + 7737488);
    unsigned short* xq    = (unsigned short*)(ws + 8137488);
    unsigned int*   txb   = (unsigned int*)(ws + 20937488);
    unsigned int*   gslab = (unsigned int*)(ws + 20937488);   // overlay, dead after k_csr

    unsigned char*  xq8 = (unsigned char*)xq;
    unsigned short* WP01 = WP;
    unsigned short* WP11 = WP + 16384;
    unsigned short* WP02 = WP + 32768;
    unsigned short* WP12 = WP + 49152;

    // CSR build (bucket sort)
    k_init <<<(NBUCK + 255) / 256, 256, 0, stream>>>(gcur);
    k_bin  <<<(NE + CHUNK - 1) / CHUNK, 256, 0, stream>>>(row, col, gcur, gslab);
    k_bscan<<<1, 256, 0, stream>>>(gcur, bbase);
    k_csr  <<<NBUCK, 256, 0, stream>>>(gslab, gcur, bbase, offs, ccol, dinv);

    k_quant<<<(NN * 64) / 256, 256, 0, stream>>>(x, dinv, xq, dsc);
    k_pack <<<(4 * 16384) / 256, 256, 0, stream>>>(W01, W11, W02, W12, WP);

    const int gatherBlocks = (NN * 64) / 256;          // 1 wave per row
    const int mmBlocks = (NSTRIP * 64 + 255) / 256;    // 1 wave per 16-row strip

    // layer 1: tx = L_hat x (int8 decode, bias 128); x1 -> int8 xq (bias 0) + dsc/s1
    k_gather<<<gatherBlocks, 256, 0, stream>>>(offs, ccol, dsc, dinv, xq, txb, 128.0f);
    k_mm    <<<mmBlocks, 256, 0, stream>>>(x, xq8, s1a, (const unsigned short*)txb,
                                           WP01, WP11, b1, dinv, out, xq8, dsc, s1a, 0);

    // layer 2: tx = L_hat x1 (bias 0); out = 0.5*(x1 + relu(x1@W0 + tx@W1 + b2))
    k_gather<<<gatherBlocks, 256, 0, stream>>>(offs, ccol, dsc, dinv, xq, txb, 0.0f);
    k_mm    <<<mmBlocks, 256, 0, stream>>>(x, xq8, s1a, (const unsigned short*)txb,
                                           WP02, WP12, b2, dinv, out, xq8, dsc, s1a, 1);
}

// Round 8
// 251.021 us; speedup vs baseline: 23.2346x; 1.1038x over previous
//
#include <hip/hip_runtime.h>

#define NN 100000
#define NE 1600000
#define NF 128
#define NSTRIP (NN / 16)                  // 6250 16-row strips
#define NBUCK ((NN + 127) / 128)          // 782 row-buckets (128 rows each)
#define CAP 2560                          // slab capacity per bucket (mean 2046, +11 sigma)
#define CHUNK 4096                        // edges per k_bin block

typedef __attribute__((ext_vector_type(8))) short short8;   // 8 bf16 (4 VGPRs)
typedef __attribute__((ext_vector_type(4))) float f32x4;    // MFMA accumulator

__device__ __forceinline__ unsigned short f2b(float f) {
    union { float f; unsigned int u; } v; v.f = f;
    unsigned int u = v.u;
    unsigned int r = (u + 0x7fffu + ((u >> 16) & 1u)) >> 16;   // RNE
    return (unsigned short)r;
}
__device__ __forceinline__ float b2f(unsigned short b) {
    return __uint_as_float(((unsigned int)b) << 16);
}

// ---------------- init bucket cursors to slab bases ----------------
__global__ __launch_bounds__(256) void k_init(int* __restrict__ gcur) {
    int i = blockIdx.x * 256 + threadIdx.x;
    if (i < NBUCK) gcur[i] = i * CAP;
}

// ---------------- phase A: LDS-binned bucket scatter ----------------
__global__ __launch_bounds__(256) void k_bin(const int* __restrict__ row,
                                             const int* __restrict__ col,
                                             int* __restrict__ gcur,
                                             unsigned int* __restrict__ gslab) {
    __shared__ int hist[NBUCK];
    __shared__ int start[NBUCK];
    __shared__ int gbase[NBUCK];
    __shared__ int scanbuf[256];
    __shared__ unsigned int stage[CHUNK];
    __shared__ unsigned short sb[CHUNK];

    const int t = threadIdx.x;
    const int e0 = blockIdx.x * CHUNK;
    const int cnt = min(CHUNK, NE - e0);

    for (int i = t; i < NBUCK; i += 256) hist[i] = 0;
    __syncthreads();
    for (int i = t; i < cnt; i += 256) atomicAdd(&hist[row[e0 + i] >> 7], 1);
    __syncthreads();

    const int b0 = t * 4;
    int s = 0;
#pragma unroll
    for (int k = 0; k < 4; ++k) { int idx = b0 + k; if (idx < NBUCK) s += hist[idx]; }
    scanbuf[t] = s;
    __syncthreads();
    for (int off = 1; off < 256; off <<= 1) {
        int u = t >= off ? scanbuf[t - off] : 0;
        __syncthreads();
        scanbuf[t] += u;
        __syncthreads();
    }
    int run = t > 0 ? scanbuf[t - 1] : 0;
#pragma unroll
    for (int k = 0; k < 4; ++k) {
        int idx = b0 + k;
        if (idx < NBUCK) { start[idx] = run; run += hist[idx]; }
    }
    __syncthreads();

    for (int i = t; i < NBUCK; i += 256) {
        int c = hist[i];
        gbase[i] = c > 0 ? atomicAdd(&gcur[i], c) : 0;
        hist[i] = start[i];
    }
    __syncthreads();

    for (int i = t; i < cnt; i += 256) {
        int r = row[e0 + i];
        int b = r >> 7;
        int p = atomicAdd(&hist[b], 1);
        stage[p] = (unsigned int)col[e0 + i] | ((unsigned int)(r & 127) << 17);
        sb[p] = (unsigned short)b;
    }
    __syncthreads();

    for (int i = t; i < cnt; i += 256) {
        int b = sb[i];
        gslab[gbase[b] + (i - start[b])] = stage[i];
    }
}

// ---------------- tiny scan of bucket counts -> CSR bucket bases ----------------
__global__ __launch_bounds__(256) void k_bscan(const int* __restrict__ gcur,
                                               int* __restrict__ bbase) {
    __shared__ int s[NBUCK];
    int t = threadIdx.x;
    for (int i = t; i < NBUCK; i += 256) s[i] = gcur[i] - i * CAP;
    __syncthreads();
    if (t == 0) {
        int run = 0;
        for (int i = 0; i < NBUCK; ++i) { int v = s[i]; s[i] = run; run += v; }
    }
    __syncthreads();
    for (int i = t; i < NBUCK; i += 256) bbase[i] = s[i];
}

// ---------------- phase B: per-bucket LDS counting sort -> offs, ccol, dinv ----
__global__ __launch_bounds__(256) void k_csr(const unsigned int* __restrict__ gslab,
                                             const int* __restrict__ gcur,
                                             const int* __restrict__ bbase,
                                             int* __restrict__ offs,
                                             int* __restrict__ ccol,
                                             float* __restrict__ dinv) {
    __shared__ int rh[128];
    __shared__ int rcur[128];
    __shared__ unsigned int scol[CAP];

    const int b = blockIdx.x;
    const int segbase = b * CAP;
    const int cnt = gcur[b] - segbase;
    const int csr0 = bbase[b];
    const int t = threadIdx.x;

    if (t < 128) rh[t] = 0;
    __syncthreads();
    for (int i = t; i < cnt; i += 256) atomicAdd(&rh[gslab[segbase + i] >> 17], 1);
    __syncthreads();
    if (t == 0) {
        int run = 0;
        for (int r = 0; r < 128; ++r) { rcur[r] = run; run += rh[r]; }
    }
    __syncthreads();

    const int rbase = b * 128;
    if (t < 128 && rbase + t < NN) {
        offs[rbase + t] = csr0 + rcur[t];
        int d = rh[t];
        dinv[rbase + t] = d > 0 ? rsqrtf((float)d) : 0.0f;
    }
    if (b == NBUCK - 1 && t == 0) offs[NN] = NE;
    __syncthreads();

    for (int i = t; i < cnt; i += 256) {
        unsigned int v = gslab[segbase + i];
        int p = atomicAdd(&rcur[v >> 17], 1);
        scol[p] = v & 0x1ffff;
    }
    __syncthreads();
    for (int i = t; i < cnt; i += 256) ccol[csr0 + i] = scol[i];
}

// ---------------- per-node int8 quantization of x (bias 128) + dsc ----------
__global__ __launch_bounds__(256) void k_quant(const float* __restrict__ x,
                                               const float* __restrict__ dinv,
                                               unsigned short* __restrict__ xq,
                                               float* __restrict__ dsc) {
    int r = (blockIdx.x * 256 + threadIdx.x) >> 6;
    int lane = threadIdx.x & 63;
    float2 v = ((const float2*)x)[r * 64 + lane];
    float m = fmaxf(fabsf(v.x), fabsf(v.y));
#pragma unroll
    for (int mask = 32; mask; mask >>= 1) m = fmaxf(m, __shfl_xor(m, mask));
    float s = m * (1.0f / 127.0f);
    float inv = m > 0.0f ? 127.0f / m : 0.0f;
    int qx = (int)rintf(v.x * inv) + 128;
    int qy = (int)rintf(v.y * inv) + 128;
    xq[r * 64 + lane] = (unsigned short)(qx | (qy << 8));
    if (lane == 0) dsc[r] = dinv[r] * s;
}

// ---------------- pack 4 weight matrices into MFMA B-fragment order ---------
// WP[mi][ ((kt*4+g)*128 + n)*8 + j ] = bf16(W[k][n]),  k = kt*32 + g*8 + j
__global__ __launch_bounds__(256) void k_pack(const float* __restrict__ W01,
                                              const float* __restrict__ W11,
                                              const float* __restrict__ W02,
                                              const float* __restrict__ W12,
                                              unsigned short* __restrict__ WP) {
    int idx = blockIdx.x * 256 + threadIdx.x;         // 4 * 16384
    int mi = idx >> 14;
    int e = idx & 16383;
    const float* W = mi == 0 ? W01 : mi == 1 ? W11 : mi == 2 ? W02 : W12;
    int k = e >> 7, n = e & 127;
    int kt = k >> 5, g = (k >> 3) & 3, j = k & 7;
    WP[mi * 16384 + (((kt * 4 + g) * 128 + n) << 3) + j] = f2b(W[e]);
}

// ---------------- gather SpMM v3: 2 edges/wave-inst, u32 (4 feats) per lane ----
// lanes 0-31 process even edges, 32-63 odd edges; fl = lane&31 owns feats 4fl..4fl+3.
// value_c = s_c*(q - qbias); sum dinv_c*value = sum dsc_c*q - qbias*sum dsc_c
__global__ __launch_bounds__(256) void k_gather(const int* __restrict__ offs,
                                                const int* __restrict__ ccol,
                                                const float* __restrict__ dsc,
                                                const float* __restrict__ dinv,
                                                const unsigned int* __restrict__ xq32,
                                                uint2* __restrict__ txb2,
                                                float qbias) {
    int r = (blockIdx.x * 256 + threadIdx.x) >> 6;
    if (r >= NN) return;
    int lane = threadIdx.x & 63;
    int fl = lane & 31, half = lane >> 5;
    int beg = offs[r], end = offs[r + 1];
    float a0 = 0.0f, a1 = 0.0f, a2 = 0.0f, a3 = 0.0f, S = 0.0f;
    int j = beg + half;                    // this lane's edges: j, j+2, j+4, ...
    for (; j + 6 < end; j += 8) {          // 4 pairs unrolled (8 edges per wave-iter)
        int c0 = ccol[j], c1 = ccol[j + 2], c2 = ccol[j + 4], c3 = ccol[j + 6];
        float w0 = dsc[c0], w1 = dsc[c1], w2 = dsc[c2], w3 = dsc[c3];
        unsigned int u0 = xq32[c0 * 32 + fl];
        unsigned int u1 = xq32[c1 * 32 + fl];
        unsigned int u2 = xq32[c2 * 32 + fl];
        unsigned int u3 = xq32[c3 * 32 + fl];
        a0 += w0 * (float)(u0 & 0xffu) + w1 * (float)(u1 & 0xffu)
            + w2 * (float)(u2 & 0xffu) + w3 * (float)(u3 & 0xffu);
        a1 += w0 * (float)((u0 >> 8) & 0xffu) + w1 * (float)((u1 >> 8) & 0xffu)
            + w2 * (float)((u2 >> 8) & 0xffu) + w3 * (float)((u3 >> 8) & 0xffu);
        a2 += w0 * (float)((u0 >> 16) & 0xffu) + w1 * (float)((u1 >> 16) & 0xffu)
            + w2 * (float)((u2 >> 16) & 0xffu) + w3 * (float)((u3 >> 16) & 0xffu);
        a3 += w0 * (float)(u0 >> 24) + w1 * (float)(u1 >> 24)
            + w2 * (float)(u2 >> 24) + w3 * (float)(u3 >> 24);
        S += w0 + w1 + w2 + w3;
    }
    for (; j < end; j += 2) {
        int c = ccol[j];
        float w = dsc[c];
        unsigned int u = xq32[c * 32 + fl];
        a0 += w * (float)(u & 0xffu);
        a1 += w * (float)((u >> 8) & 0xffu);
        a2 += w * (float)((u >> 16) & 0xffu);
        a3 += w * (float)(u >> 24);
        S += w;
    }
    // combine even/odd halves (feature fl*4+k lives in lanes fl and fl+32)
    a0 += __shfl_xor(a0, 32);
    a1 += __shfl_xor(a1, 32);
    a2 += __shfl_xor(a2, 32);
    a3 += __shfl_xor(a3, 32);
    S  += __shfl_xor(S, 32);
    if (half == 0) {
        float s = -dinv[r];
        a0 = s * (a0 - qbias * S);
        a1 = s * (a1 - qbias * S);
        a2 = s * (a2 - qbias * S);
        a3 = s * (a3 - qbias * S);
        uint2 o;
        o.x = (unsigned int)f2b(a0) | ((unsigned int)f2b(a1) << 16);
        o.y = (unsigned int)f2b(a2) | ((unsigned int)f2b(a3) << 16);
        txb2[r * 32 + fl] = o;
    }
}

// ---------------- MFMA dual-GEMM: relu(A@W0 + T@W1 + b) ----------------
// mode 0: A from fp32 x; writes x1 as int8 (bias 0) + dsc/s1.
// mode 1: A from int8 x1 (decode with s1); out = 0.5*(x1 + relu(acc)).
__global__ __launch_bounds__(256) void k_mm(const float* __restrict__ Axf,
                                            const unsigned char* __restrict__ Aq,
                                            const float* __restrict__ s1_in,
                                            const unsigned short* __restrict__ Tbf,
                                            const unsigned short* __restrict__ WP0,
                                            const unsigned short* __restrict__ WP1,
                                            const float* __restrict__ bias,
                                            const float* __restrict__ dinv,
                                            float* __restrict__ out,
                                            unsigned char* __restrict__ Qout,
                                            float* __restrict__ dsc_out,
                                            float* __restrict__ s1_out,
                                            int mode) {
    int wid = (blockIdx.x * 256 + threadIdx.x) >> 6;
    if (wid >= NSTRIP) return;
    int lane = threadIdx.x & 63;
    int g = lane >> 4, m = lane & 15;

    short8 a[4], t[4];
    if (mode == 0) {
        const float* Arow = Axf + (size_t)(wid * 16 + m) * NF + g * 8;
#pragma unroll
        for (int kt = 0; kt < 4; ++kt) {
            float4 f0 = *(const float4*)(Arow + kt * 32);
            float4 f1 = *(const float4*)(Arow + kt * 32 + 4);
            short8 v;
            v[0] = f2b(f0.x); v[1] = f2b(f0.y); v[2] = f2b(f0.z); v[3] = f2b(f0.w);
            v[4] = f2b(f1.x); v[5] = f2b(f1.y); v[6] = f2b(f1.z); v[7] = f2b(f1.w);
            a[kt] = v;
        }
    } else {
        float sA = s1_in[wid * 16 + m];
        const unsigned char* Arow = Aq + (size_t)(wid * 16 + m) * NF + g * 8;
#pragma unroll
        for (int kt = 0; kt < 4; ++kt) {
            uint2 u = *(const uint2*)(Arow + kt * 32);
            short8 v;
            v[0] = f2b(sA * (float)(u.x & 0xffu));
            v[1] = f2b(sA * (float)((u.x >> 8) & 0xffu));
            v[2] = f2b(sA * (float)((u.x >> 16) & 0xffu));
            v[3] = f2b(sA * (float)(u.x >> 24));
            v[4] = f2b(sA * (float)(u.y & 0xffu));
            v[5] = f2b(sA * (float)((u.y >> 8) & 0xffu));
            v[6] = f2b(sA * (float)((u.y >> 16) & 0xffu));
            v[7] = f2b(sA * (float)(u.y >> 24));
            a[kt] = v;
        }
    }

    const short8* Tfr = (const short8*)(Tbf + (size_t)(wid * 16 + m) * NF + g * 8);
#pragma unroll
    for (int kt = 0; kt < 4; ++kt) t[kt] = Tfr[kt * 4];

    const short8* B0 = (const short8*)WP0 + g * 128 + m;   // + kt*512 + nt*16
    const short8* B1 = (const short8*)WP1 + g * 128 + m;

    f32x4 acc[8];
#pragma unroll
    for (int nt = 0; nt < 8; ++nt) {
        float b = bias[nt * 16 + m];
        acc[nt][0] = b; acc[nt][1] = b; acc[nt][2] = b; acc[nt][3] = b;
    }

#pragma unroll
    for (int nt = 0; nt < 8; ++nt) {
#pragma unroll
        for (int kt = 0; kt < 4; ++kt) {
            acc[nt] = __builtin_amdgcn_mfma_f32_16x16x32_bf16(a[kt], B0[kt * 512 + nt * 16], acc[nt], 0, 0, 0);
            acc[nt] = __builtin_amdgcn_mfma_f32_16x16x32_bf16(t[kt], B1[kt * 512 + nt * 16], acc[nt], 0, 0, 0);
        }
    }

    // relu
#pragma unroll
    for (int nt = 0; nt < 8; ++nt)
#pragma unroll
        for (int r = 0; r < 4; ++r) acc[nt][r] = fmaxf(acc[nt][r], 0.0f);

    int rbase = wid * 16 + g * 4;   // D: col = nt*16 + m, row = rbase + r
    if (mode == 0) {
        float mr[4] = {0.0f, 0.0f, 0.0f, 0.0f};
#pragma unroll
        for (int nt = 0; nt < 8; ++nt)
#pragma unroll
            for (int r = 0; r < 4; ++r) mr[r] = fmaxf(mr[r], acc[nt][r]);
#pragma unroll
        for (int mask = 1; mask < 16; mask <<= 1)
#pragma unroll
            for (int r = 0; r < 4; ++r) mr[r] = fmaxf(mr[r], __shfl_xor(mr[r], mask));

        float inv[4], s1v[4];
#pragma unroll
        for (int r = 0; r < 4; ++r) {
            s1v[r] = mr[r] * (1.0f / 255.0f);
            inv[r] = mr[r] > 0.0f ? 255.0f / mr[r] : 0.0f;
        }
#pragma unroll
        for (int nt = 0; nt < 8; ++nt) {
            int c = nt * 16 + m;
#pragma unroll
            for (int r = 0; r < 4; ++r) {
                int q = (int)rintf(acc[nt][r] * inv[r]);
                q = q > 255 ? 255 : q;
                Qout[(size_t)(rbase + r) * NF + c] = (unsigned char)q;
            }
        }
        if (m == 0) {
#pragma unroll
            for (int r = 0; r < 4; ++r) {
                s1_out[rbase + r] = s1v[r];
                dsc_out[rbase + r] = dinv[rbase + r] * s1v[r];
            }
        }
    } else {
        float sR[4];
#pragma unroll
        for (int r = 0; r < 4; ++r) sR[r] = s1_in[rbase + r];
#pragma unroll
        for (int nt = 0; nt < 8; ++nt) {
            int c = nt * 16 + m;
#pragma unroll
            for (int r = 0; r < 4; ++r) {
                size_t o = (size_t)(rbase + r) * NF + c;
                float x1v = sR[r] * (float)Aq[o];
                out[o] = 0.5f * (x1v + acc[nt][r]);
            }
        }
    }
}

extern "C" void kernel_launch(void* const* d_in, const int* in_sizes, int n_in,
                              void* d_out, int out_size, void* d_ws, size_t ws_size,
                              hipStream_t stream) {
    const float* x   = (const float*)d_in[0];
    const int*   ei  = (const int*)d_in[1];
    const float* W01 = (const float*)d_in[2];
    const float* W11 = (const float*)d_in[3];
    const float* b1  = (const float*)d_in[4];
    const float* W02 = (const float*)d_in[5];
    const float* W12 = (const float*)d_in[6];
    const float* b2  = (const float*)d_in[7];
    float* out = (float*)d_out;

    const int* row = ei;        // edge_index[0]
    const int* col = ei + NE;   // edge_index[1]

    // ws layout (bytes), total 46,537,488:
    //   gcur  @ 0         (3200)
    //   bbase @ 3200      (3200)      -> 6400
    //   dinv  @ 6400      (400000)    -> 406400
    //   offs  @ 406400    (400016)    -> 806416
    //   ccol  @ 806416    (6400000)   -> 7206416
    //   WP    @ 7206416   (131072)    -> 7337488   (4 bf16 weight frag sets)
    //   dsc   @ 7337488   (400000)    -> 7737488   (dinv*scale, per layer)
    //   s1a   @ 7737488   (400000)    -> 8137488   (x1 per-row scale)
    //   xq    @ 8137488   (12800000)  -> 20937488  (int8 x, then int8 x1)
    //   txb   @ 20937488  (25600000)  -> 46537488  (bf16 tx; gslab overlays pre-gather)
    char* ws = (char*)d_ws;
    int*            gcur  = (int*)(ws);
    int*            bbase = (int*)(ws + 3200);
    float*          dinv  = (float*)(ws + 6400);
    int*            offs  = (int*)(ws + 406400);
    int*            ccol  = (int*)(ws + 806416);
    unsigned short* WP    = (unsigned short*)(ws + 7206416);
    float*          dsc   = (float*)(ws + 7337488);
    float*          s1a   = (float*)(ws + 7737488);
    unsigned short* xq    = (unsigned short*)(ws + 8137488);
    unsigned int*   txb   = (unsigned int*)(ws + 20937488);
    unsigned int*   gslab = (unsigned int*)(ws + 20937488);   // overlay, dead after k_csr

    unsigned char*  xq8 = (unsigned char*)xq;
    unsigned short* WP01 = WP;
    unsigned short* WP11 = WP + 16384;
    unsigned short* WP02 = WP + 32768;
    unsigned short* WP12 = WP + 49152;

    // CSR build (bucket sort)
    k_init <<<(NBUCK + 255) / 256, 256, 0, stream>>>(gcur);
    k_bin  <<<(NE + CHUNK - 1) / CHUNK, 256, 0, stream>>>(row, col, gcur, gslab);
    k_bscan<<<1, 256, 0, stream>>>(gcur, bbase);
    k_csr  <<<NBUCK, 256, 0, stream>>>(gslab, gcur, bbase, offs, ccol, dinv);

    k_quant<<<(NN * 64) / 256, 256, 0, stream>>>(x, dinv, xq, dsc);
    k_pack <<<(4 * 16384) / 256, 256, 0, stream>>>(W01, W11, W02, W12, WP);

    const int gatherBlocks = (NN * 64) / 256;          // 1 wave per row
    const int mmBlocks = (NSTRIP * 64 + 255) / 256;    // 1 wave per 16-row strip

    // layer 1: tx = L_hat x (int8 decode, bias 128); x1 -> int8 xq (bias 0) + dsc/s1
    k_gather<<<gatherBlocks, 256, 0, stream>>>(offs, ccol, dsc, dinv,
                                               (const unsigned int*)xq, (uint2*)txb, 128.0f);
    k_mm    <<<mmBlocks, 256, 0, stream>>>(x, xq8, s1a, (const unsigned short*)txb,
                                           WP01, WP11, b1, dinv, out, xq8, dsc, s1a, 0);

    // layer 2: tx = L_hat x1 (bias 0); out = 0.5*(x1 + relu(x1@W0 + tx@W1 + b2))
    k_gather<<<gatherBlocks, 256, 0, stream>>>(offs, ccol, dsc, dinv,
                                               (const unsigned int*)xq, (uint2*)txb, 0.0f);
    k_mm    <<<mmBlocks, 256, 0, stream>>>(x, xq8, s1a, (const unsigned short*)txb,
                                           WP02, WP12, b2, dinv, out, xq8, dsc, s1a, 1);
}

// Round 9
// 246.180 us; speedup vs baseline: 23.6915x; 1.0197x over previous
//
#include <hip/hip_runtime.h>

#define NN 100000
#define NE 1600000
#define NF 128
#define NSTRIP (NN / 16)                  // 6250 16-row strips
#define NBUCK ((NN + 127) / 128)          // 782 row-buckets (128 rows each)
#define CAP 2560                          // slab capacity per bucket (mean 2046, +11 sigma)
#define CHUNK 4096                        // edges per k_bin block

typedef __attribute__((ext_vector_type(8))) short short8;   // 8 bf16 (4 VGPRs)
typedef __attribute__((ext_vector_type(4))) float f32x4;    // MFMA accumulator

__device__ __forceinline__ unsigned short f2b(float f) {
    union { float f; unsigned int u; } v; v.f = f;
    unsigned int u = v.u;
    unsigned int r = (u + 0x7fffu + ((u >> 16) & 1u)) >> 16;   // RNE
    return (unsigned short)r;
}
__device__ __forceinline__ float b2f(unsigned short b) {
    return __uint_as_float(((unsigned int)b) << 16);
}

// ---------------- init bucket cursors to slab bases ----------------
__global__ __launch_bounds__(256) void k_init(int* __restrict__ gcur) {
    int i = blockIdx.x * 256 + threadIdx.x;
    if (i < NBUCK) gcur[i] = i * CAP;
}

// ---------------- phase A: LDS-binned bucket scatter ----------------
__global__ __launch_bounds__(256) void k_bin(const int* __restrict__ row,
                                             const int* __restrict__ col,
                                             int* __restrict__ gcur,
                                             unsigned int* __restrict__ gslab) {
    __shared__ int hist[NBUCK];
    __shared__ int start[NBUCK];
    __shared__ int gbase[NBUCK];
    __shared__ int scanbuf[256];
    __shared__ unsigned int stage[CHUNK];
    __shared__ unsigned short sb[CHUNK];

    const int t = threadIdx.x;
    const int e0 = blockIdx.x * CHUNK;
    const int cnt = min(CHUNK, NE - e0);

    for (int i = t; i < NBUCK; i += 256) hist[i] = 0;
    __syncthreads();
    for (int i = t; i < cnt; i += 256) atomicAdd(&hist[row[e0 + i] >> 7], 1);
    __syncthreads();

    const int b0 = t * 4;
    int s = 0;
#pragma unroll
    for (int k = 0; k < 4; ++k) { int idx = b0 + k; if (idx < NBUCK) s += hist[idx]; }
    scanbuf[t] = s;
    __syncthreads();
    for (int off = 1; off < 256; off <<= 1) {
        int u = t >= off ? scanbuf[t - off] : 0;
        __syncthreads();
        scanbuf[t] += u;
        __syncthreads();
    }
    int run = t > 0 ? scanbuf[t - 1] : 0;
#pragma unroll
    for (int k = 0; k < 4; ++k) {
        int idx = b0 + k;
        if (idx < NBUCK) { start[idx] = run; run += hist[idx]; }
    }
    __syncthreads();

    for (int i = t; i < NBUCK; i += 256) {
        int c = hist[i];
        gbase[i] = c > 0 ? atomicAdd(&gcur[i], c) : 0;
        hist[i] = start[i];
    }
    __syncthreads();

    for (int i = t; i < cnt; i += 256) {
        int r = row[e0 + i];
        int b = r >> 7;
        int p = atomicAdd(&hist[b], 1);
        stage[p] = (unsigned int)col[e0 + i] | ((unsigned int)(r & 127) << 17);
        sb[p] = (unsigned short)b;
    }
    __syncthreads();

    for (int i = t; i < cnt; i += 256) {
        int b = sb[i];
        gslab[gbase[b] + (i - start[b])] = stage[i];
    }
}

// ---------------- tiny scan of bucket counts -> CSR bucket bases ----------------
__global__ __launch_bounds__(256) void k_bscan(const int* __restrict__ gcur,
                                               int* __restrict__ bbase) {
    __shared__ int s[NBUCK];
    int t = threadIdx.x;
    for (int i = t; i < NBUCK; i += 256) s[i] = gcur[i] - i * CAP;
    __syncthreads();
    if (t == 0) {
        int run = 0;
        for (int i = 0; i < NBUCK; ++i) { int v = s[i]; s[i] = run; run += v; }
    }
    __syncthreads();
    for (int i = t; i < NBUCK; i += 256) bbase[i] = s[i];
}

// ---------------- phase B: per-bucket LDS counting sort -> offs, ccol, dinv ----
__global__ __launch_bounds__(256) void k_csr(const unsigned int* __restrict__ gslab,
                                             const int* __restrict__ gcur,
                                             const int* __restrict__ bbase,
                                             int* __restrict__ offs,
                                             int* __restrict__ ccol,
                                             float* __restrict__ dinv) {
    __shared__ int rh[128];
    __shared__ int rcur[128];
    __shared__ unsigned int scol[CAP];

    const int b = blockIdx.x;
    const int segbase = b * CAP;
    const int cnt = gcur[b] - segbase;
    const int csr0 = bbase[b];
    const int t = threadIdx.x;

    if (t < 128) rh[t] = 0;
    __syncthreads();
    for (int i = t; i < cnt; i += 256) atomicAdd(&rh[gslab[segbase + i] >> 17], 1);
    __syncthreads();
    if (t == 0) {
        int run = 0;
        for (int r = 0; r < 128; ++r) { rcur[r] = run; run += rh[r]; }
    }
    __syncthreads();

    const int rbase = b * 128;
    if (t < 128 && rbase + t < NN) {
        offs[rbase + t] = csr0 + rcur[t];
        int d = rh[t];
        dinv[rbase + t] = d > 0 ? rsqrtf((float)d) : 0.0f;
    }
    if (b == NBUCK - 1 && t == 0) offs[NN] = NE;
    __syncthreads();

    for (int i = t; i < cnt; i += 256) {
        unsigned int v = gslab[segbase + i];
        int p = atomicAdd(&rcur[v >> 17], 1);
        scol[p] = v & 0x1ffff;
    }
    __syncthreads();
    for (int i = t; i < cnt; i += 256) ccol[csr0 + i] = scol[i];
}

// ---------------- per-node int8 quantization of x (bias 128) + dsc ----------
__global__ __launch_bounds__(256) void k_quant(const float* __restrict__ x,
                                               const float* __restrict__ dinv,
                                               unsigned short* __restrict__ xq,
                                               float* __restrict__ dsc) {
    int r = (blockIdx.x * 256 + threadIdx.x) >> 6;
    int lane = threadIdx.x & 63;
    float2 v = ((const float2*)x)[r * 64 + lane];
    float m = fmaxf(fabsf(v.x), fabsf(v.y));
#pragma unroll
    for (int mask = 32; mask; mask >>= 1) m = fmaxf(m, __shfl_xor(m, mask));
    float s = m * (1.0f / 127.0f);
    float inv = m > 0.0f ? 127.0f / m : 0.0f;
    int qx = (int)rintf(v.x * inv) + 128;
    int qy = (int)rintf(v.y * inv) + 128;
    xq[r * 64 + lane] = (unsigned short)(qx | (qy << 8));
    if (lane == 0) dsc[r] = dinv[r] * s;
}

// ---------------- pack 4 weight matrices into MFMA B-fragment order ---------
// WP[mi][ ((kt*4+g)*128 + n)*8 + j ] = bf16(W[k][n]),  k = kt*32 + g*8 + j
__global__ __launch_bounds__(256) void k_pack(const float* __restrict__ W01,
                                              const float* __restrict__ W11,
                                              const float* __restrict__ W02,
                                              const float* __restrict__ W12,
                                              unsigned short* __restrict__ WP) {
    int idx = blockIdx.x * 256 + threadIdx.x;         // 4 * 16384
    int mi = idx >> 14;
    int e = idx & 16383;
    const float* W = mi == 0 ? W01 : mi == 1 ? W02 : mi == 2 ? W11 : W12;
    int midx = mi == 0 ? 0 : mi == 1 ? 2 : mi == 2 ? 1 : 3;
    int k = e >> 7, n = e & 127;
    int kt = k >> 5, g = (k >> 3) & 3, j = k & 7;
    WP[midx * 16384 + (((kt * 4 + g) * 128 + n) << 3) + j] = f2b(W[e]);
}

// ---------------- gather SpMM v4: 4 edges/wave-inst, uint2 (8 feats) per lane --
// lane = q*16+fl; quarter q handles edges beg+q, beg+q+4, ...; fl owns feats
// 8fl..8fl+7. value_c = s_c*(q - qbias); result combined via shfl_xor 32,16.
__global__ __launch_bounds__(256) void k_gather(const int* __restrict__ offs,
                                                const int* __restrict__ ccol,
                                                const float* __restrict__ dsc,
                                                const float* __restrict__ dinv,
                                                const uint2* __restrict__ xq64,
                                                uint4* __restrict__ txb4,
                                                float qbias) {
    int r = (blockIdx.x * 256 + threadIdx.x) >> 6;
    if (r >= NN) return;
    int lane = threadIdx.x & 63;
    int fl = lane & 15, q = lane >> 4;
    int beg = offs[r], end = offs[r + 1];
    float a0 = 0.f, a1 = 0.f, a2 = 0.f, a3 = 0.f;
    float a4 = 0.f, a5 = 0.f, a6 = 0.f, a7 = 0.f, S = 0.f;
    int j = beg + q;                       // this quarter's edges: j, j+4, j+8...
    for (; j + 4 < end; j += 8) {          // 2 edges/quarter per iter (8 edges/wave)
        int c0 = ccol[j], c1 = ccol[j + 4];
        float w0 = dsc[c0], w1 = dsc[c1];
        uint2 u0 = xq64[c0 * 16 + fl];
        uint2 u1 = xq64[c1 * 16 + fl];
        a0 += w0 * (float)(u0.x & 0xffu)         + w1 * (float)(u1.x & 0xffu);
        a1 += w0 * (float)((u0.x >> 8) & 0xffu)  + w1 * (float)((u1.x >> 8) & 0xffu);
        a2 += w0 * (float)((u0.x >> 16) & 0xffu) + w1 * (float)((u1.x >> 16) & 0xffu);
        a3 += w0 * (float)(u0.x >> 24)           + w1 * (float)(u1.x >> 24);
        a4 += w0 * (float)(u0.y & 0xffu)         + w1 * (float)(u1.y & 0xffu);
        a5 += w0 * (float)((u0.y >> 8) & 0xffu)  + w1 * (float)((u1.y >> 8) & 0xffu);
        a6 += w0 * (float)((u0.y >> 16) & 0xffu) + w1 * (float)((u1.y >> 16) & 0xffu);
        a7 += w0 * (float)(u0.y >> 24)           + w1 * (float)(u1.y >> 24);
        S += w0 + w1;
    }
    for (; j < end; j += 4) {
        int c = ccol[j];
        float w = dsc[c];
        uint2 u = xq64[c * 16 + fl];
        a0 += w * (float)(u.x & 0xffu);
        a1 += w * (float)((u.x >> 8) & 0xffu);
        a2 += w * (float)((u.x >> 16) & 0xffu);
        a3 += w * (float)(u.x >> 24);
        a4 += w * (float)(u.y & 0xffu);
        a5 += w * (float)((u.y >> 8) & 0xffu);
        a6 += w * (float)((u.y >> 16) & 0xffu);
        a7 += w * (float)(u.y >> 24);
        S += w;
    }
    // combine 4 quarters: lanes fl, fl+16, fl+32, fl+48
#pragma unroll
    for (int mask = 32; mask >= 16; mask >>= 1) {
        a0 += __shfl_xor(a0, mask); a1 += __shfl_xor(a1, mask);
        a2 += __shfl_xor(a2, mask); a3 += __shfl_xor(a3, mask);
        a4 += __shfl_xor(a4, mask); a5 += __shfl_xor(a5, mask);
        a6 += __shfl_xor(a6, mask); a7 += __shfl_xor(a7, mask);
        S  += __shfl_xor(S, mask);
    }
    if (q == 0) {
        float s = -dinv[r];
        float qb = qbias * S;
        a0 = s * (a0 - qb); a1 = s * (a1 - qb); a2 = s * (a2 - qb); a3 = s * (a3 - qb);
        a4 = s * (a4 - qb); a5 = s * (a5 - qb); a6 = s * (a6 - qb); a7 = s * (a7 - qb);
        uint4 o;
        o.x = (unsigned int)f2b(a0) | ((unsigned int)f2b(a1) << 16);
        o.y = (unsigned int)f2b(a2) | ((unsigned int)f2b(a3) << 16);
        o.z = (unsigned int)f2b(a4) | ((unsigned int)f2b(a5) << 16);
        o.w = (unsigned int)f2b(a6) | ((unsigned int)f2b(a7) << 16);
        txb4[r * 16 + fl] = o;
    }
}

// ---------------- MFMA dual-GEMM: relu(A@W0 + T@W1 + b) ----------------
// mode 0: A from fp32 x; writes x1 as int8 (bias 0) + dsc/s1.
// mode 1: A from int8 x1 (decode with s1); out = 0.5*(x1 + relu(acc)).
__global__ __launch_bounds__(256) void k_mm(const float* __restrict__ Axf,
                                            const unsigned char* __restrict__ Aq,
                                            const float* __restrict__ s1_in,
                                            const unsigned short* __restrict__ Tbf,
                                            const unsigned short* __restrict__ WP0,
                                            const unsigned short* __restrict__ WP1,
                                            const float* __restrict__ bias,
                                            const float* __restrict__ dinv,
                                            float* __restrict__ out,
                                            unsigned char* __restrict__ Qout,
                                            float* __restrict__ dsc_out,
                                            float* __restrict__ s1_out,
                                            int mode) {
    int wid = (blockIdx.x * 256 + threadIdx.x) >> 6;
    if (wid >= NSTRIP) return;
    int lane = threadIdx.x & 63;
    int g = lane >> 4, m = lane & 15;

    short8 a[4], t[4];
    if (mode == 0) {
        const float* Arow = Axf + (size_t)(wid * 16 + m) * NF + g * 8;
#pragma unroll
        for (int kt = 0; kt < 4; ++kt) {
            float4 f0 = *(const float4*)(Arow + kt * 32);
            float4 f1 = *(const float4*)(Arow + kt * 32 + 4);
            short8 v;
            v[0] = f2b(f0.x); v[1] = f2b(f0.y); v[2] = f2b(f0.z); v[3] = f2b(f0.w);
            v[4] = f2b(f1.x); v[5] = f2b(f1.y); v[6] = f2b(f1.z); v[7] = f2b(f1.w);
            a[kt] = v;
        }
    } else {
        float sA = s1_in[wid * 16 + m];
        const unsigned char* Arow = Aq + (size_t)(wid * 16 + m) * NF + g * 8;
#pragma unroll
        for (int kt = 0; kt < 4; ++kt) {
            uint2 u = *(const uint2*)(Arow + kt * 32);
            short8 v;
            v[0] = f2b(sA * (float)(u.x & 0xffu));
            v[1] = f2b(sA * (float)((u.x >> 8) & 0xffu));
            v[2] = f2b(sA * (float)((u.x >> 16) & 0xffu));
            v[3] = f2b(sA * (float)(u.x >> 24));
            v[4] = f2b(sA * (float)(u.y & 0xffu));
            v[5] = f2b(sA * (float)((u.y >> 8) & 0xffu));
            v[6] = f2b(sA * (float)((u.y >> 16) & 0xffu));
            v[7] = f2b(sA * (float)(u.y >> 24));
            a[kt] = v;
        }
    }

    const short8* Tfr = (const short8*)(Tbf + (size_t)(wid * 16 + m) * NF + g * 8);
#pragma unroll
    for (int kt = 0; kt < 4; ++kt) t[kt] = Tfr[kt * 4];

    const short8* B0 = (const short8*)WP0 + g * 128 + m;   // + kt*512 + nt*16
    const short8* B1 = (const short8*)WP1 + g * 128 + m;

    f32x4 acc[8];
#pragma unroll
    for (int nt = 0; nt < 8; ++nt) {
        float b = bias[nt * 16 + m];
        acc[nt][0] = b; acc[nt][1] = b; acc[nt][2] = b; acc[nt][3] = b;
    }

#pragma unroll
    for (int nt = 0; nt < 8; ++nt) {
#pragma unroll
        for (int kt = 0; kt < 4; ++kt) {
            acc[nt] = __builtin_amdgcn_mfma_f32_16x16x32_bf16(a[kt], B0[kt * 512 + nt * 16], acc[nt], 0, 0, 0);
            acc[nt] = __builtin_amdgcn_mfma_f32_16x16x32_bf16(t[kt], B1[kt * 512 + nt * 16], acc[nt], 0, 0, 0);
        }
    }

    // relu
#pragma unroll
    for (int nt = 0; nt < 8; ++nt)
#pragma unroll
        for (int r = 0; r < 4; ++r) acc[nt][r] = fmaxf(acc[nt][r], 0.0f);

    int rbase = wid * 16 + g * 4;   // D: col = nt*16 + m, row = rbase + r
    if (mode == 0) {
        float mr[4] = {0.0f, 0.0f, 0.0f, 0.0f};
#pragma unroll
        for (int nt = 0; nt < 8; ++nt)
#pragma unroll
            for (int r = 0; r < 4; ++r) mr[r] = fmaxf(mr[r], acc[nt][r]);
#pragma unroll
        for (int mask = 1; mask < 16; mask <<= 1)
#pragma unroll
            for (int r = 0; r < 4; ++r) mr[r] = fmaxf(mr[r], __shfl_xor(mr[r], mask));

        float inv[4], s1v[4];
#pragma unroll
        for (int r = 0; r < 4; ++r) {
            s1v[r] = mr[r] * (1.0f / 255.0f);
            inv[r] = mr[r] > 0.0f ? 255.0f / mr[r] : 0.0f;
        }
#pragma unroll
        for (int nt = 0; nt < 8; ++nt) {
            int c = nt * 16 + m;
#pragma unroll
            for (int r = 0; r < 4; ++r) {
                int q = (int)rintf(acc[nt][r] * inv[r]);
                q = q > 255 ? 255 : q;
                Qout[(size_t)(rbase + r) * NF + c] = (unsigned char)q;
            }
        }
        if (m == 0) {
#pragma unroll
            for (int r = 0; r < 4; ++r) {
                s1_out[rbase + r] = s1v[r];
                dsc_out[rbase + r] = dinv[rbase + r] * s1v[r];
            }
        }
    } else {
        float sR[4];
#pragma unroll
        for (int r = 0; r < 4; ++r) sR[r] = s1_in[rbase + r];
#pragma unroll
        for (int nt = 0; nt < 8; ++nt) {
            int c = nt * 16 + m;
#pragma unroll
            for (int r = 0; r < 4; ++r) {
                size_t o = (size_t)(rbase + r) * NF + c;
                float x1v = sR[r] * (float)Aq[o];
                out[o] = 0.5f * (x1v + acc[nt][r]);
            }
        }
    }
}

extern "C" void kernel_launch(void* const* d_in, const int* in_sizes, int n_in,
                              void* d_out, int out_size, void* d_ws, size_t ws_size,
                              hipStream_t stream) {
    const float* x   = (const float*)d_in[0];
    const int*   ei  = (const int*)d_in[1];
    const float* W01 = (const float*)d_in[2];
    const float* W11 = (const float*)d_in[3];
    const float* b1  = (const float*)d_in[4];
    const float* W02 = (const float*)d_in[5];
    const float* W12 = (const float*)d_in[6];
    const float* b2  = (const float*)d_in[7];
    float* out = (float*)d_out;

    const int* row = ei;        // edge_index[0]
    const int* col = ei + NE;   // edge_index[1]

    // ws layout (bytes), total 46,537,488:
    //   gcur  @ 0         (3200)
    //   bbase @ 3200      (3200)      -> 6400
    //   dinv  @ 6400      (400000)    -> 406400
    //   offs  @ 406400    (400016)    -> 806416
    //   ccol  @ 806416    (6400000)   -> 7206416
    //   WP    @ 7206416   (131072)    -> 7337488   (4 bf16 weight frag sets)
    //   dsc   @ 7337488   (400000)    -> 7737488   (dinv*scale, per layer)
    //   s1a   @ 7737488   (400000)    -> 8137488   (x1 per-row scale)
    //   xq    @ 8137488   (12800000)  -> 20937488  (int8 x, then int8 x1)
    //   txb   @ 20937488  (25600000)  -> 46537488  (bf16 tx; gslab overlays pre-gather)
    char* ws = (char*)d_ws;
    int*            gcur  = (int*)(ws);
    int*            bbase = (int*)(ws + 3200);
    float*          dinv  = (float*)(ws + 6400);
    int*            offs  = (int*)(ws + 406400);
    int*            ccol  = (int*)(ws + 806416);
    unsigned short* WP    = (unsigned short*)(ws + 7206416);
    float*          dsc   = (float*)(ws + 7337488);
    float*          s1a   = (float*)(ws + 7737488);
    unsigned short* xq    = (unsigned short*)(ws + 8137488);
    unsigned int*   txb   = (unsigned int*)(ws + 20937488);
    unsigned int*   gslab = (unsigned int*)(ws + 20937488);   // overlay, dead after k_csr

    unsigned char*  xq8 = (unsigned char*)xq;
    unsigned short* WP01 = WP;
    unsigned short* WP11 = WP + 16384;
    unsigned short* WP02 = WP + 32768;
    unsigned short* WP12 = WP + 49152;

    // CSR build (bucket sort)
    k_init <<<(NBUCK + 255) / 256, 256, 0, stream>>>(gcur);
    k_bin  <<<(NE + CHUNK - 1) / CHUNK, 256, 0, stream>>>(row, col, gcur, gslab);
    k_bscan<<<1, 256, 0, stream>>>(gcur, bbase);
    k_csr  <<<NBUCK, 256, 0, stream>>>(gslab, gcur, bbase, offs, ccol, dinv);

    k_quant<<<(NN * 64) / 256, 256, 0, stream>>>(x, dinv, xq, dsc);
    k_pack <<<(4 * 16384) / 256, 256, 0, stream>>>(W01, W11, W02, W12, WP);

    const int gatherBlocks = (NN * 64) / 256;          // 1 wave per row
    const int mmBlocks = (NSTRIP * 64 + 255) / 256;    // 1 wave per 16-row strip

    // layer 1: tx = L_hat x (int8 decode, bias 128); x1 -> int8 xq (bias 0) + dsc/s1
    k_gather<<<gatherBlocks, 256, 0, stream>>>(offs, ccol, dsc, dinv,
                                               (const uint2*)xq, (uint4*)txb, 128.0f);
    k_mm    <<<mmBlocks, 256, 0, stream>>>(x, xq8, s1a, (const unsigned short*)txb,
                                           WP01, WP11, b1, dinv, out, xq8, dsc, s1a, 0);

    // layer 2: tx = L_hat x1 (bias 0); out = 0.5*(x1 + relu(x1@W0 + tx@W1 + b2))
    k_gather<<<gatherBlocks, 256, 0, stream>>>(offs, ccol, dsc, dinv,
                                               (const uint2*)xq, (uint4*)txb, 0.0f);
    k_mm    <<<mmBlocks, 256, 0, stream>>>(x, xq8, s1a, (const unsigned short*)txb,
                                           WP02, WP12, b2, dinv, out, xq8, dsc, s1a, 1);
}

// Round 10
// 245.023 us; speedup vs baseline: 23.8034x; 1.0047x over previous
//
#include <hip/hip_runtime.h>

#define NN 100000
#define NE 1600000
#define NF 128
#define NSTRIP (NN / 16)                  // 6250 16-row strips
#define NBUCK ((NN + 127) / 128)          // 782 row-buckets (128 rows each)
#define CAP 2560                          // slab capacity per bucket (mean 2046, +11 sigma)
#define CHUNK 4096                        // edges per k_bin block

typedef __attribute__((ext_vector_type(8))) short short8;   // 8 bf16 (4 VGPRs)
typedef __attribute__((ext_vector_type(4))) float f32x4;    // MFMA accumulator

__device__ __forceinline__ unsigned short f2b(float f) {
    union { float f; unsigned int u; } v; v.f = f;
    unsigned int u = v.u;
    unsigned int r = (u + 0x7fffu + ((u >> 16) & 1u)) >> 16;   // RNE
    return (unsigned short)r;
}

// ---------------- init bucket cursors to slab bases ----------------
__global__ __launch_bounds__(256) void k_init(int* __restrict__ gcur) {
    int i = blockIdx.x * 256 + threadIdx.x;
    if (i < NBUCK) gcur[i] = i * CAP;
}

// ---------------- phase A: LDS-binned bucket scatter ----------------
__global__ __launch_bounds__(256) void k_bin(const int* __restrict__ row,
                                             const int* __restrict__ col,
                                             int* __restrict__ gcur,
                                             unsigned int* __restrict__ gslab) {
    __shared__ int hist[NBUCK];
    __shared__ int start[NBUCK];
    __shared__ int gbase[NBUCK];
    __shared__ int scanbuf[256];
    __shared__ unsigned int stage[CHUNK];
    __shared__ unsigned short sb[CHUNK];

    const int t = threadIdx.x;
    const int e0 = blockIdx.x * CHUNK;
    const int cnt = min(CHUNK, NE - e0);

    for (int i = t; i < NBUCK; i += 256) hist[i] = 0;
    __syncthreads();
    for (int i = t; i < cnt; i += 256) atomicAdd(&hist[row[e0 + i] >> 7], 1);
    __syncthreads();

    const int b0 = t * 4;
    int s = 0;
#pragma unroll
    for (int k = 0; k < 4; ++k) { int idx = b0 + k; if (idx < NBUCK) s += hist[idx]; }
    scanbuf[t] = s;
    __syncthreads();
    for (int off = 1; off < 256; off <<= 1) {
        int u = t >= off ? scanbuf[t - off] : 0;
        __syncthreads();
        scanbuf[t] += u;
        __syncthreads();
    }
    int run = t > 0 ? scanbuf[t - 1] : 0;
#pragma unroll
    for (int k = 0; k < 4; ++k) {
        int idx = b0 + k;
        if (idx < NBUCK) { start[idx] = run; run += hist[idx]; }
    }
    __syncthreads();

    for (int i = t; i < NBUCK; i += 256) {
        int c = hist[i];
        gbase[i] = c > 0 ? atomicAdd(&gcur[i], c) : 0;
        hist[i] = start[i];
    }
    __syncthreads();

    for (int i = t; i < cnt; i += 256) {
        int r = row[e0 + i];
        int b = r >> 7;
        int p = atomicAdd(&hist[b], 1);
        stage[p] = (unsigned int)col[e0 + i] | ((unsigned int)(r & 127) << 17);
        sb[p] = (unsigned short)b;
    }
    __syncthreads();

    for (int i = t; i < cnt; i += 256) {
        int b = sb[i];
        gslab[gbase[b] + (i - start[b])] = stage[i];
    }
}

// ---------------- tiny scan of bucket counts -> CSR bucket bases ----------------
__global__ __launch_bounds__(256) void k_bscan(const int* __restrict__ gcur,
                                               int* __restrict__ bbase) {
    __shared__ int s[NBUCK];
    int t = threadIdx.x;
    for (int i = t; i < NBUCK; i += 256) s[i] = gcur[i] - i * CAP;
    __syncthreads();
    if (t == 0) {
        int run = 0;
        for (int i = 0; i < NBUCK; ++i) { int v = s[i]; s[i] = run; run += v; }
    }
    __syncthreads();
    for (int i = t; i < NBUCK; i += 256) bbase[i] = s[i];
}

// ---------------- phase B: per-bucket LDS counting sort -> offs, ccol, dinv ----
__global__ __launch_bounds__(256) void k_csr(const unsigned int* __restrict__ gslab,
                                             const int* __restrict__ gcur,
                                             const int* __restrict__ bbase,
                                             int* __restrict__ offs,
                                             int* __restrict__ ccol,
                                             float* __restrict__ dinv) {
    __shared__ int rh[128];
    __shared__ int rcur[128];
    __shared__ unsigned int scol[CAP];

    const int b = blockIdx.x;
    const int segbase = b * CAP;
    const int cnt = gcur[b] - segbase;
    const int csr0 = bbase[b];
    const int t = threadIdx.x;

    if (t < 128) rh[t] = 0;
    __syncthreads();
    for (int i = t; i < cnt; i += 256) atomicAdd(&rh[gslab[segbase + i] >> 17], 1);
    __syncthreads();
    if (t == 0) {
        int run = 0;
        for (int r = 0; r < 128; ++r) { rcur[r] = run; run += rh[r]; }
    }
    __syncthreads();

    const int rbase = b * 128;
    if (t < 128 && rbase + t < NN) {
        offs[rbase + t] = csr0 + rcur[t];
        int d = rh[t];
        dinv[rbase + t] = d > 0 ? rsqrtf((float)d) : 0.0f;
    }
    if (b == NBUCK - 1 && t == 0) offs[NN] = NE;
    __syncthreads();

    for (int i = t; i < cnt; i += 256) {
        unsigned int v = gslab[segbase + i];
        int p = atomicAdd(&rcur[v >> 17], 1);
        scol[p] = v & 0x1ffff;
    }
    __syncthreads();
    for (int i = t; i < cnt; i += 256) ccol[csr0 + i] = scol[i];
}

// ---------------- per-node int8 quantization of x (bias 128) + dsc + sx ------
__global__ __launch_bounds__(256) void k_quant(const float* __restrict__ x,
                                               const float* __restrict__ dinv,
                                               unsigned short* __restrict__ xq,
                                               float* __restrict__ dsc,
                                               float* __restrict__ sx) {
    int r = (blockIdx.x * 256 + threadIdx.x) >> 6;
    int lane = threadIdx.x & 63;
    float2 v = ((const float2*)x)[r * 64 + lane];
    float m = fmaxf(fabsf(v.x), fabsf(v.y));
#pragma unroll
    for (int mask = 32; mask; mask >>= 1) m = fmaxf(m, __shfl_xor(m, mask));
    float s = m * (1.0f / 127.0f);
    float inv = m > 0.0f ? 127.0f / m : 0.0f;
    int qx = (int)rintf(v.x * inv) + 128;
    int qy = (int)rintf(v.y * inv) + 128;
    xq[r * 64 + lane] = (unsigned short)(qx | (qy << 8));
    if (lane == 0) { dsc[r] = dinv[r] * s; sx[r] = s; }
}

// ---------------- pack 4 weight matrices into MFMA B-fragment order ---------
// WP[mi][ ((kt*4+g)*128 + n)*8 + j ] = bf16(W[k][n]),  k = kt*32 + g*8 + j
__global__ __launch_bounds__(256) void k_pack(const float* __restrict__ W01,
                                              const float* __restrict__ W11,
                                              const float* __restrict__ W02,
                                              const float* __restrict__ W12,
                                              unsigned short* __restrict__ WP) {
    int idx = blockIdx.x * 256 + threadIdx.x;         // 4 * 16384
    int mi = idx >> 14;
    int e = idx & 16383;
    const float* W = mi == 0 ? W01 : mi == 1 ? W02 : mi == 2 ? W11 : W12;
    int midx = mi == 0 ? 0 : mi == 1 ? 2 : mi == 2 ? 1 : 3;
    int k = e >> 7, n = e & 127;
    int kt = k >> 5, g = (k >> 3) & 3, j = k & 7;
    WP[midx * 16384 + (((kt * 4 + g) * 128 + n) << 3) + j] = f2b(W[e]);
}

// ---------------- gather SpMM v5: 16 edges in flight, uint2 (8 feats)/lane ----
// lane = q*16+fl; quarter q handles edges beg+q, beg+q+4, ...; fl owns feats
// 8fl..8fl+7. Main loop: 4 edges/quarter (16/wave). Combined via shfl_xor 32,16.
__global__ __launch_bounds__(256) void k_gather(const int* __restrict__ offs,
                                                const int* __restrict__ ccol,
                                                const float* __restrict__ dsc,
                                                const float* __restrict__ dinv,
                                                const uint2* __restrict__ xq64,
                                                uint4* __restrict__ txb4,
                                                float qbias) {
    int r = (blockIdx.x * 256 + threadIdx.x) >> 6;
    if (r >= NN) return;
    int lane = threadIdx.x & 63;
    int fl = lane & 15, q = lane >> 4;
    int beg = offs[r], end = offs[r + 1];
    float a0 = 0.f, a1 = 0.f, a2 = 0.f, a3 = 0.f;
    float a4 = 0.f, a5 = 0.f, a6 = 0.f, a7 = 0.f, S = 0.f;
    int j = beg + q;                       // this quarter's edges: j, j+4, j+8...
    for (; j + 12 < end; j += 16) {        // 4 edges/quarter per iter (16/wave)
        int c0 = ccol[j], c1 = ccol[j + 4], c2 = ccol[j + 8], c3 = ccol[j + 12];
        float w0 = dsc[c0], w1 = dsc[c1], w2 = dsc[c2], w3 = dsc[c3];
        uint2 u0 = xq64[c0 * 16 + fl];
        uint2 u1 = xq64[c1 * 16 + fl];
        uint2 u2 = xq64[c2 * 16 + fl];
        uint2 u3 = xq64[c3 * 16 + fl];
        a0 += w0 * (float)(u0.x & 0xffu)         + w1 * (float)(u1.x & 0xffu)
            + w2 * (float)(u2.x & 0xffu)         + w3 * (float)(u3.x & 0xffu);
        a1 += w0 * (float)((u0.x >> 8) & 0xffu)  + w1 * (float)((u1.x >> 8) & 0xffu)
            + w2 * (float)((u2.x >> 8) & 0xffu)  + w3 * (float)((u3.x >> 8) & 0xffu);
        a2 += w0 * (float)((u0.x >> 16) & 0xffu) + w1 * (float)((u1.x >> 16) & 0xffu)
            + w2 * (float)((u2.x >> 16) & 0xffu) + w3 * (float)((u3.x >> 16) & 0xffu);
        a3 += w0 * (float)(u0.x >> 24)           + w1 * (float)(u1.x >> 24)
            + w2 * (float)(u2.x >> 24)           + w3 * (float)(u3.x >> 24);
        a4 += w0 * (float)(u0.y & 0xffu)         + w1 * (float)(u1.y & 0xffu)
            + w2 * (float)(u2.y & 0xffu)         + w3 * (float)(u3.y & 0xffu);
        a5 += w0 * (float)((u0.y >> 8) & 0xffu)  + w1 * (float)((u1.y >> 8) & 0xffu)
            + w2 * (float)((u2.y >> 8) & 0xffu)  + w3 * (float)((u3.y >> 8) & 0xffu);
        a6 += w0 * (float)((u0.y >> 16) & 0xffu) + w1 * (float)((u1.y >> 16) & 0xffu)
            + w2 * (float)((u2.y >> 16) & 0xffu) + w3 * (float)((u3.y >> 16) & 0xffu);
        a7 += w0 * (float)(u0.y >> 24)           + w1 * (float)(u1.y >> 24)
            + w2 * (float)(u2.y >> 24)           + w3 * (float)(u3.y >> 24);
        S += w0 + w1 + w2 + w3;
    }
    for (; j < end; j += 4) {
        int c = ccol[j];
        float w = dsc[c];
        uint2 u = xq64[c * 16 + fl];
        a0 += w * (float)(u.x & 0xffu);
        a1 += w * (float)((u.x >> 8) & 0xffu);
        a2 += w * (float)((u.x >> 16) & 0xffu);
        a3 += w * (float)(u.x >> 24);
        a4 += w * (float)(u.y & 0xffu);
        a5 += w * (float)((u.y >> 8) & 0xffu);
        a6 += w * (float)((u.y >> 16) & 0xffu);
        a7 += w * (float)(u.y >> 24);
        S += w;
    }
    // combine 4 quarters: lanes fl, fl+16, fl+32, fl+48
#pragma unroll
    for (int mask = 32; mask >= 16; mask >>= 1) {
        a0 += __shfl_xor(a0, mask); a1 += __shfl_xor(a1, mask);
        a2 += __shfl_xor(a2, mask); a3 += __shfl_xor(a3, mask);
        a4 += __shfl_xor(a4, mask); a5 += __shfl_xor(a5, mask);
        a6 += __shfl_xor(a6, mask); a7 += __shfl_xor(a7, mask);
        S  += __shfl_xor(S, mask);
    }
    if (q == 0) {
        float s = -dinv[r];
        float qb = qbias * S;
        a0 = s * (a0 - qb); a1 = s * (a1 - qb); a2 = s * (a2 - qb); a3 = s * (a3 - qb);
        a4 = s * (a4 - qb); a5 = s * (a5 - qb); a6 = s * (a6 - qb); a7 = s * (a7 - qb);
        uint4 o;
        o.x = (unsigned int)f2b(a0) | ((unsigned int)f2b(a1) << 16);
        o.y = (unsigned int)f2b(a2) | ((unsigned int)f2b(a3) << 16);
        o.z = (unsigned int)f2b(a4) | ((unsigned int)f2b(a5) << 16);
        o.w = (unsigned int)f2b(a6) | ((unsigned int)f2b(a7) << 16);
        txb4[r * 16 + fl] = o;
    }
}

// ---------------- MFMA dual-GEMM: relu(A@W0 + T@W1 + b) ----------------
// A decoded from int8 (per-row scale s_in, bias qoff).
// mode 0: writes x1 as int8 (bias 0) + dsc/s1.  mode 1: out = 0.5*(x1 + relu).
__global__ __launch_bounds__(256) void k_mm(const unsigned char* __restrict__ Aq,
                                            const float* __restrict__ s_in,
                                            float qoff,
                                            const unsigned short* __restrict__ Tbf,
                                            const unsigned short* __restrict__ WP0,
                                            const unsigned short* __restrict__ WP1,
                                            const float* __restrict__ bias,
                                            const float* __restrict__ dinv,
                                            float* __restrict__ out,
                                            unsigned char* __restrict__ Qout,
                                            float* __restrict__ dsc_out,
                                            float* __restrict__ s1_out,
                                            int mode) {
    int wid = (blockIdx.x * 256 + threadIdx.x) >> 6;
    if (wid >= NSTRIP) return;
    int lane = threadIdx.x & 63;
    int g = lane >> 4, m = lane & 15;

    short8 a[4], t[4];
    {
        float sA = s_in[wid * 16 + m];
        const unsigned char* Arow = Aq + (size_t)(wid * 16 + m) * NF + g * 8;
#pragma unroll
        for (int kt = 0; kt < 4; ++kt) {
            uint2 u = *(const uint2*)(Arow + kt * 32);
            short8 v;
            v[0] = f2b(sA * ((float)(u.x & 0xffu) - qoff));
            v[1] = f2b(sA * ((float)((u.x >> 8) & 0xffu) - qoff));
            v[2] = f2b(sA * ((float)((u.x >> 16) & 0xffu) - qoff));
            v[3] = f2b(sA * ((float)(u.x >> 24) - qoff));
            v[4] = f2b(sA * ((float)(u.y & 0xffu) - qoff));
            v[5] = f2b(sA * ((float)((u.y >> 8) & 0xffu) - qoff));
            v[6] = f2b(sA * ((float)((u.y >> 16) & 0xffu) - qoff));
            v[7] = f2b(sA * ((float)(u.y >> 24) - qoff));
            a[kt] = v;
        }
    }

    const short8* Tfr = (const short8*)(Tbf + (size_t)(wid * 16 + m) * NF + g * 8);
#pragma unroll
    for (int kt = 0; kt < 4; ++kt) t[kt] = Tfr[kt * 4];

    const short8* B0 = (const short8*)WP0 + g * 128 + m;   // + kt*512 + nt*16
    const short8* B1 = (const short8*)WP1 + g * 128 + m;

    f32x4 acc[8];
#pragma unroll
    for (int nt = 0; nt < 8; ++nt) {
        float b = bias[nt * 16 + m];
        acc[nt][0] = b; acc[nt][1] = b; acc[nt][2] = b; acc[nt][3] = b;
    }

#pragma unroll
    for (int nt = 0; nt < 8; ++nt) {
#pragma unroll
        for (int kt = 0; kt < 4; ++kt) {
            acc[nt] = __builtin_amdgcn_mfma_f32_16x16x32_bf16(a[kt], B0[kt * 512 + nt * 16], acc[nt], 0, 0, 0);
            acc[nt] = __builtin_amdgcn_mfma_f32_16x16x32_bf16(t[kt], B1[kt * 512 + nt * 16], acc[nt], 0, 0, 0);
        }
    }

    // relu
#pragma unroll
    for (int nt = 0; nt < 8; ++nt)
#pragma unroll
        for (int r = 0; r < 4; ++r) acc[nt][r] = fmaxf(acc[nt][r], 0.0f);

    int rbase = wid * 16 + g * 4;   // D: col = nt*16 + m, row = rbase + r
    if (mode == 0) {
        float mr[4] = {0.0f, 0.0f, 0.0f, 0.0f};
#pragma unroll
        for (int nt = 0; nt < 8; ++nt)
#pragma unroll
            for (int r = 0; r < 4; ++r) mr[r] = fmaxf(mr[r], acc[nt][r]);
#pragma unroll
        for (int mask = 1; mask < 16; mask <<= 1)
#pragma unroll
            for (int r = 0; r < 4; ++r) mr[r] = fmaxf(mr[r], __shfl_xor(mr[r], mask));

        float inv[4], s1v[4];
#pragma unroll
        for (int r = 0; r < 4; ++r) {
            s1v[r] = mr[r] * (1.0f / 255.0f);
            inv[r] = mr[r] > 0.0f ? 255.0f / mr[r] : 0.0f;
        }
#pragma unroll
        for (int nt = 0; nt < 8; ++nt) {
            int c = nt * 16 + m;
#pragma unroll
            for (int r = 0; r < 4; ++r) {
                int q = (int)rintf(acc[nt][r] * inv[r]);
                q = q > 255 ? 255 : q;
                Qout[(size_t)(rbase + r) * NF + c] = (unsigned char)q;
            }
        }
        if (m == 0) {
#pragma unroll
            for (int r = 0; r < 4; ++r) {
                s1_out[rbase + r] = s1v[r];
                dsc_out[rbase + r] = dinv[rbase + r] * s1v[r];
            }
        }
    } else {
        float sR[4];
#pragma unroll
        for (int r = 0; r < 4; ++r) sR[r] = s_in[rbase + r];
#pragma unroll
        for (int nt = 0; nt < 8; ++nt) {
            int c = nt * 16 + m;
#pragma unroll
            for (int r = 0; r < 4; ++r) {
                size_t o = (size_t)(rbase + r) * NF + c;
                float x1v = sR[r] * (float)Aq[o];
                out[o] = 0.5f * (x1v + acc[nt][r]);
            }
        }
    }
}

extern "C" void kernel_launch(void* const* d_in, const int* in_sizes, int n_in,
                              void* d_out, int out_size, void* d_ws, size_t ws_size,
                              hipStream_t stream) {
    const float* x   = (const float*)d_in[0];
    const int*   ei  = (const int*)d_in[1];
    const float* W01 = (const float*)d_in[2];
    const float* W11 = (const float*)d_in[3];
    const float* b1  = (const float*)d_in[4];
    const float* W02 = (const float*)d_in[5];
    const float* W12 = (const float*)d_in[6];
    const float* b2  = (const float*)d_in[7];
    float* out = (float*)d_out;

    const int* row = ei;        // edge_index[0]
    const int* col = ei + NE;   // edge_index[1]

    // ws layout (bytes), total 46,937,488:
    //   gcur  @ 0         (3200)
    //   bbase @ 3200      (3200)      -> 6400
    //   dinv  @ 6400      (400000)    -> 406400
    //   offs  @ 406400    (400016)    -> 806416
    //   ccol  @ 806416    (6400000)   -> 7206416
    //   WP    @ 7206416   (131072)    -> 7337488   (4 bf16 weight frag sets)
    //   dsc   @ 7337488   (400000)    -> 7737488   (dinv*scale, per layer)
    //   s1a   @ 7737488   (400000)    -> 8137488   (x1 per-row scale)
    //   sx    @ 8137488   (400000)    -> 8537488   (x per-row scale)
    //   xq    @ 8537488   (12800000)  -> 21337488  (int8 x, then int8 x1)
    //   txb   @ 21337488  (25600000)  -> 46937488  (bf16 tx; gslab overlays pre-gather)
    char* ws = (char*)d_ws;
    int*            gcur  = (int*)(ws);
    int*            bbase = (int*)(ws + 3200);
    float*          dinv  = (float*)(ws + 6400);
    int*            offs  = (int*)(ws + 406400);
    int*            ccol  = (int*)(ws + 806416);
    unsigned short* WP    = (unsigned short*)(ws + 7206416);
    float*          dsc   = (float*)(ws + 7337488);
    float*          s1a   = (float*)(ws + 7737488);
    float*          sx    = (float*)(ws + 8137488);
    unsigned short* xq    = (unsigned short*)(ws + 8537488);
    unsigned int*   txb   = (unsigned int*)(ws + 21337488);
    unsigned int*   gslab = (unsigned int*)(ws + 21337488);   // overlay, dead after k_csr

    unsigned char*  xq8 = (unsigned char*)xq;
    unsigned short* WP01 = WP;
    unsigned short* WP11 = WP + 16384;
    unsigned short* WP02 = WP + 32768;
    unsigned short* WP12 = WP + 49152;

    // CSR build (bucket sort)
    k_init <<<(NBUCK + 255) / 256, 256, 0, stream>>>(gcur);
    k_bin  <<<(NE + CHUNK - 1) / CHUNK, 256, 0, stream>>>(row, col, gcur, gslab);
    k_bscan<<<1, 256, 0, stream>>>(gcur, bbase);
    k_csr  <<<NBUCK, 256, 0, stream>>>(gslab, gcur, bbase, offs, ccol, dinv);

    k_quant<<<(NN * 64) / 256, 256, 0, stream>>>(x, dinv, xq, dsc, sx);
    k_pack <<<(4 * 16384) / 256, 256, 0, stream>>>(W01, W11, W02, W12, WP);

    const int gatherBlocks = (NN * 64) / 256;          // 1 wave per row
    const int mmBlocks = (NSTRIP * 64 + 255) / 256;    // 1 wave per 16-row strip

    // layer 1: tx = L_hat x (int8 decode, bias 128); x1 -> int8 xq (bias 0) + dsc/s1
    k_gather<<<gatherBlocks, 256, 0, stream>>>(offs, ccol, dsc, dinv,
                                               (const uint2*)xq, (uint4*)txb, 128.0f);
    k_mm    <<<mmBlocks, 256, 0, stream>>>(xq8, sx, 128.0f, (const unsigned short*)txb,
                                           WP01, WP11, b1, dinv, out, xq8, dsc, s1a, 0);

    // layer 2: tx = L_hat x1 (bias 0); out = 0.5*(x1 + relu(x1@W0 + tx@W1 + b2))
    k_gather<<<gatherBlocks, 256, 0, stream>>>(offs, ccol, dsc, dinv,
                                               (const uint2*)xq, (uint4*)txb, 0.0f);
    k_mm    <<<mmBlocks, 256, 0, stream>>>(xq8, s1a, 0.0f, (const unsigned short*)txb,
                                           WP02, WP12, b2, dinv, out, xq8, dsc, s1a, 1);
}